// Round 1
// baseline (7559.269 us; speedup 1.0000x reference)
//
#include <hip/hip_runtime.h>

// Problem constants (match reference setup_inputs)
constexpr int NU  = 100000;   // users
constexpr int NA  = 20000;    // apps
constexpr int FU  = 32;
constexpr int FA  = 64;
constexpr int H   = 128;
constexpr int NE  = 1000000;  // edges per direction
constexpr int NEL = 500000;   // labeled pairs

// ---------------------------------------------------------------------------
// Prologue: out[i,:] = emb[nid[i],:] + x[i,:] @ W + b   (one row per block)
// ---------------------------------------------------------------------------
template <int F>
__global__ __launch_bounds__(128)
void prologue_kernel(const float* __restrict__ x,    // [N,F]
                     const float* __restrict__ emb,  // [N,H] (gathered via nid)
                     const float* __restrict__ W,    // [F,H]
                     const float* __restrict__ b,    // [H]
                     const int*   __restrict__ nid,  // [N]
                     float* __restrict__ out,        // [N,H]
                     int N) {
    __shared__ float xs[F];
    int row = blockIdx.x;
    if (row >= N) return;
    int t = threadIdx.x;  // 0..127 (== output column)
    if (t < F) xs[t] = x[(size_t)row * F + t];
    __syncthreads();
    int id = nid[row];
    float acc = emb[(size_t)id * H + t] + b[t];
#pragma unroll
    for (int k = 0; k < F; ++k) acc += xs[k] * W[k * H + t];
    out[(size_t)row * H + t] = acc;
}

// ---------------------------------------------------------------------------
// Scatter-add aggregation: agg[dst,:] += xsrc[src,:], cnt[dst] += 1
// 32 threads per edge, each handling 4 contiguous floats (float4 gather).
// ---------------------------------------------------------------------------
__global__ __launch_bounds__(256)
void scatter_kernel(const float* __restrict__ xsrc,  // [Nsrc,H]
                    const int*   __restrict__ esrc,  // [E]
                    const int*   __restrict__ edst,  // [E]
                    float* __restrict__ agg,         // [Ndst,H]
                    float* __restrict__ cnt,         // [Ndst]
                    int E) {
    long long idx = (long long)blockIdx.x * blockDim.x + threadIdx.x;
    int e = (int)(idx >> 5);
    if (e >= E) return;
    int q = (int)(idx & 31);
    int s = esrc[e];
    int d = edst[e];
    const float4 v = *reinterpret_cast<const float4*>(xsrc + (size_t)s * H + q * 4);
    float* p = agg + (size_t)d * H + q * 4;
    unsafeAtomicAdd(p + 0, v.x);
    unsafeAtomicAdd(p + 1, v.y);
    unsafeAtomicAdd(p + 2, v.z);
    unsafeAtomicAdd(p + 3, v.w);
    if (q == 0) unsafeAtomicAdd(cnt + d, 1.0f);
}

// ---------------------------------------------------------------------------
// SAGE epilogue: out[i,:] = [relu]( (agg[i,:]/max(cnt[i],1)) @ Wm
//                                   + xdst[i,:] @ Ws + b )
// Block of 128 threads handles RT=16 rows; thread t owns output column t.
// out may alias agg is NOT allowed here (different buffers used by caller);
// out may alias a buffer whose rows are fully staged in LDS before writing.
// ---------------------------------------------------------------------------
template <bool RELU>
__global__ __launch_bounds__(128)
void sage_kernel(const float* __restrict__ agg,   // [N,H]
                 const float* __restrict__ cnt,   // [N]
                 const float* __restrict__ xdst,  // [N,H]
                 const float* __restrict__ Wm,    // [H,H]
                 const float* __restrict__ Ws,    // [H,H]
                 const float* __restrict__ b,     // [H]
                 float* __restrict__ out,         // [N,H]
                 int N) {
    constexpr int RT = 16;
    __shared__ float aS[RT][H];
    __shared__ float xS[RT][H];
    __shared__ float sc[RT];
    int row0 = blockIdx.x * RT;
    int t = threadIdx.x;
    if (t < RT) {
        int r = row0 + t;
        float c = (r < N) ? cnt[r] : 1.0f;
        sc[t] = 1.0f / fmaxf(c, 1.0f);
    }
    __syncthreads();
#pragma unroll
    for (int r = 0; r < RT; ++r) {
        int row = row0 + r;
        if (row < N) {
            aS[r][t] = agg[(size_t)row * H + t] * sc[r];
            xS[r][t] = xdst[(size_t)row * H + t];
        } else {
            aS[r][t] = 0.0f;
            xS[r][t] = 0.0f;
        }
    }
    __syncthreads();
    float acc[RT];
    float bb = b[t];
#pragma unroll
    for (int r = 0; r < RT; ++r) acc[r] = bb;
#pragma unroll 4
    for (int k = 0; k < H; ++k) {
        float wm = Wm[k * H + t];
        float ws = Ws[k * H + t];
#pragma unroll
        for (int r = 0; r < RT; ++r) acc[r] += aS[r][k] * wm + xS[r][k] * ws;
    }
#pragma unroll
    for (int r = 0; r < RT; ++r) {
        int row = row0 + r;
        if (row < N) {
            float v = acc[r];
            if (RELU) v = fmaxf(v, 0.0f);
            out[(size_t)row * H + t] = v;
        }
    }
}

// ---------------------------------------------------------------------------
// Head: pred[e] = dot(xu2[el_src[e],:], xa2[el_dst[e],:])  (one wave per pair)
// ---------------------------------------------------------------------------
__global__ __launch_bounds__(256)
void pred_kernel(const float* __restrict__ xu,  // [NU,H]
                 const float* __restrict__ xa,  // [NA,H]
                 const int* __restrict__ esrc,  // [EL]
                 const int* __restrict__ edst,  // [EL]
                 float* __restrict__ out,       // [EL]
                 int E) {
    long long idx = (long long)blockIdx.x * blockDim.x + threadIdx.x;
    int e = (int)(idx >> 6);
    if (e >= E) return;
    int l = (int)(idx & 63);
    int s = esrc[e];
    int d = edst[e];
    const float* pu = xu + (size_t)s * H;
    const float* pa = xa + (size_t)d * H;
    float v = pu[l] * pa[l] + pu[l + 64] * pa[l + 64];
#pragma unroll
    for (int off = 32; off > 0; off >>= 1) v += __shfl_down(v, off);
    if (l == 0) out[e] = v;
}

// ---------------------------------------------------------------------------
extern "C" void kernel_launch(void* const* d_in, const int* in_sizes, int n_in,
                              void* d_out, int out_size, void* d_ws, size_t ws_size,
                              hipStream_t stream) {
    // inputs in setup_inputs dict order
    const float* user_x     = (const float*)d_in[0];
    const float* app_x      = (const float*)d_in[1];
    const float* user_emb   = (const float*)d_in[2];
    const float* app_emb    = (const float*)d_in[3];
    const float* user_lin_W = (const float*)d_in[4];
    const float* user_lin_b = (const float*)d_in[5];
    const float* app_lin_W  = (const float*)d_in[6];
    const float* app_lin_b  = (const float*)d_in[7];
    const float* W_msg_ua1  = (const float*)d_in[8];
    const float* W_self_ua1 = (const float*)d_in[9];
    const float* b_ua1      = (const float*)d_in[10];
    const float* W_msg_au1  = (const float*)d_in[11];
    const float* W_self_au1 = (const float*)d_in[12];
    const float* b_au1      = (const float*)d_in[13];
    const float* W_msg_ua2  = (const float*)d_in[14];
    const float* W_self_ua2 = (const float*)d_in[15];
    const float* b_ua2      = (const float*)d_in[16];
    const float* W_msg_au2  = (const float*)d_in[17];
    const float* W_self_au2 = (const float*)d_in[18];
    const float* b_au2      = (const float*)d_in[19];
    const int*   user_n_id  = (const int*)d_in[20];
    const int*   app_n_id   = (const int*)d_in[21];
    const int*   e_src_u2a  = (const int*)d_in[22];
    const int*   e_dst_u2a  = (const int*)d_in[23];
    const int*   e_src_a2u  = (const int*)d_in[24];
    const int*   e_dst_a2u  = (const int*)d_in[25];
    const int*   el_src     = (const int*)d_in[26];
    const int*   el_dst     = (const int*)d_in[27];
    float* pred = (float*)d_out;

    // workspace layout (floats)
    float* ws = (float*)d_ws;
    size_t off = 0;
    float* AGGU = ws + off; off += (size_t)NU * H;
    float* CNTU = ws + off; off += NU;          // contiguous with AGGU (one memset)
    float* AGGA = ws + off; off += (size_t)NA * H;
    float* CNTA = ws + off; off += NA;          // contiguous with AGGA
    float* XU0  = ws + off; off += (size_t)NU * H;  // xu0, later xu2
    float* XU1  = ws + off; off += (size_t)NU * H;
    float* XA0  = ws + off; off += (size_t)NA * H;  // xa0, later xa2
    float* XA1  = ws + off; off += (size_t)NA * H;
    (void)ws_size; (void)in_sizes; (void)n_in; (void)out_size;

    const int sgrid = (int)(((long long)NE * 32 + 255) / 256);
    const int pgrid = (int)(((long long)NEL * 64 + 255) / 256);

    // prologue
    prologue_kernel<FU><<<NU, 128, 0, stream>>>(user_x, user_emb, user_lin_W,
                                                user_lin_b, user_n_id, XU0, NU);
    prologue_kernel<FA><<<NA, 128, 0, stream>>>(app_x, app_emb, app_lin_W,
                                                app_lin_b, app_n_id, XA0, NA);

    // layer 1, user->app: xa1 = relu(mean_agg(xu0) @ Wm + xa0 @ Ws + b)
    hipMemsetAsync(AGGA, 0, ((size_t)NA * H + NA) * sizeof(float), stream);
    scatter_kernel<<<sgrid, 256, 0, stream>>>(XU0, e_src_u2a, e_dst_u2a, AGGA, CNTA, NE);
    sage_kernel<true><<<NA / 16, 128, 0, stream>>>(AGGA, CNTA, XA0, W_msg_ua1,
                                                   W_self_ua1, b_ua1, XA1, NA);

    // layer 1, app->user: xu1 = relu(mean_agg(xa0) @ Wm + xu0 @ Ws + b)
    hipMemsetAsync(AGGU, 0, ((size_t)NU * H + NU) * sizeof(float), stream);
    scatter_kernel<<<sgrid, 256, 0, stream>>>(XA0, e_src_a2u, e_dst_a2u, AGGU, CNTU, NE);
    sage_kernel<true><<<NU / 16, 128, 0, stream>>>(AGGU, CNTU, XU0, W_msg_au1,
                                                   W_self_au1, b_au1, XU1, NU);

    // layer 2, user->app: xa2 = mean_agg(xu1) @ Wm + xa1 @ Ws + b   (into XA0)
    hipMemsetAsync(AGGA, 0, ((size_t)NA * H + NA) * sizeof(float), stream);
    scatter_kernel<<<sgrid, 256, 0, stream>>>(XU1, e_src_u2a, e_dst_u2a, AGGA, CNTA, NE);
    sage_kernel<false><<<NA / 16, 128, 0, stream>>>(AGGA, CNTA, XA1, W_msg_ua2,
                                                    W_self_ua2, b_ua2, XA0, NA);

    // layer 2, app->user: xu2 = mean_agg(xa1) @ Wm + xu1 @ Ws + b   (into XU0)
    hipMemsetAsync(AGGU, 0, ((size_t)NU * H + NU) * sizeof(float), stream);
    scatter_kernel<<<sgrid, 256, 0, stream>>>(XA1, e_src_a2u, e_dst_a2u, AGGU, CNTU, NE);
    sage_kernel<false><<<NU / 16, 128, 0, stream>>>(AGGU, CNTU, XU1, W_msg_au2,
                                                    W_self_au2, b_au2, XU0, NU);

    // head
    pred_kernel<<<pgrid, 256, 0, stream>>>(XU0, XA0, el_src, el_dst, pred, NEL);
}

// Round 2
// 1363.117 us; speedup vs baseline: 5.5456x; 5.5456x over previous
//
#include <hip/hip_runtime.h>

// Problem constants (match reference setup_inputs)
constexpr int NU  = 100000;   // users
constexpr int NA  = 20000;    // apps
constexpr int FU  = 32;
constexpr int FA  = 64;
constexpr int H   = 128;
constexpr int NE  = 1000000;  // edges per direction
constexpr int NEL = 500000;   // labeled pairs

// ---------------------------------------------------------------------------
// Prologue: out[i,:] = emb[nid[i],:] + x[i,:] @ W + b   (one row per block)
// ---------------------------------------------------------------------------
template <int F>
__global__ __launch_bounds__(128)
void prologue_kernel(const float* __restrict__ x,    // [N,F]
                     const float* __restrict__ emb,  // [N,H]
                     const float* __restrict__ W,    // [F,H]
                     const float* __restrict__ b,    // [H]
                     const int*   __restrict__ nid,  // [N]
                     float* __restrict__ out,        // [N,H]
                     int N) {
    __shared__ float xs[F];
    int row = blockIdx.x;
    if (row >= N) return;
    int t = threadIdx.x;  // 0..127 (== output column)
    if (t < F) xs[t] = x[(size_t)row * F + t];
    __syncthreads();
    int id = nid[row];
    float acc = emb[(size_t)id * H + t] + b[t];
#pragma unroll
    for (int k = 0; k < F; ++k) acc += xs[k] * W[k * H + t];
    out[(size_t)row * H + t] = acc;
}

// ---------------------------------------------------------------------------
// CSR build: histogram -> scan -> fill (dst-sorted src-index lists)
// ---------------------------------------------------------------------------
__global__ __launch_bounds__(256)
void hist_kernel(const int* __restrict__ edst, int* __restrict__ deg, int E) {
    int e = blockIdx.x * blockDim.x + threadIdx.x;
    if (e < E) atomicAdd(&deg[edst[e]], 1);
}

// per-1024-block inclusive scan; writes per-element inclusive + block sums
__global__ __launch_bounds__(1024)
void scan1_kernel(const int* __restrict__ deg, int* __restrict__ incl,
                  int* __restrict__ bsum, int N) {
    __shared__ int s[1024];
    int t = threadIdx.x;
    int i = blockIdx.x * 1024 + t;
    s[t] = (i < N) ? deg[i] : 0;
    __syncthreads();
    for (int d = 1; d < 1024; d <<= 1) {
        int add = (t >= d) ? s[t - d] : 0;
        __syncthreads();
        s[t] += add;
        __syncthreads();
    }
    if (i < N) incl[i] = s[t];
    if (t == 1023) bsum[blockIdx.x] = s[1023];
}

// single-block inclusive scan of block sums (nb <= 1024)
__global__ __launch_bounds__(1024)
void scan2_kernel(int* __restrict__ bsum, int nb) {
    __shared__ int s[1024];
    int t = threadIdx.x;
    s[t] = (t < nb) ? bsum[t] : 0;
    __syncthreads();
    for (int d = 1; d < 1024; d <<= 1) {
        int add = (t >= d) ? s[t - d] : 0;
        __syncthreads();
        s[t] += add;
        __syncthreads();
    }
    if (t < nb) bsum[t] = s[t];
}

// row_ptr[i+1] = incl[i] + offset(block);  row_ptr[0] = 0
__global__ __launch_bounds__(256)
void scan3_kernel(const int* __restrict__ incl, const int* __restrict__ bsum,
                  int* __restrict__ row_ptr, int N) {
    int i = blockIdx.x * 256 + threadIdx.x;
    if (i == 0) row_ptr[0] = 0;
    if (i < N) {
        int blk = i >> 10;
        int off = (blk > 0) ? bsum[blk - 1] : 0;
        row_ptr[i + 1] = incl[i] + off;
    }
}

__global__ __launch_bounds__(256)
void fill_kernel(const int* __restrict__ esrc, const int* __restrict__ edst,
                 const int* __restrict__ row_ptr, int* __restrict__ fill,
                 int* __restrict__ eidx, int E) {
    int e = blockIdx.x * blockDim.x + threadIdx.x;
    if (e >= E) return;
    int d = edst[e];
    int pos = row_ptr[d] + atomicAdd(&fill[d], 1);
    eidx[pos] = esrc[e];
}

// ---------------------------------------------------------------------------
// Fused SAGE: per block, aggregate RT dst rows (CSR gather, mean) into LDS,
// stage self rows, then out = aggS @ Wm + selfS @ Ws + b  [+relu].
// thread t owns output column t.
// ---------------------------------------------------------------------------
template <bool RELU, int RT>
__global__ __launch_bounds__(128)
void sage_fused(const float* __restrict__ xsrc,     // [Nsrc,H] gather source
                const int*   __restrict__ row_ptr,  // [N+1]
                const int*   __restrict__ eidx,     // [E] src indices, dst-sorted
                const float* __restrict__ xdst,     // [N,H] self features
                const float* __restrict__ Wm,       // [H,H]
                const float* __restrict__ Ws,       // [H,H]
                const float* __restrict__ b,        // [H]
                float* __restrict__ out,            // [N,H]
                int N) {
    __shared__ float aS[RT][H];
    __shared__ float xS[RT][H];
    int row0 = blockIdx.x * RT;
    int t = threadIdx.x;
    for (int r = 0; r < RT; ++r) {
        int row = row0 + r;
        int beg = row_ptr[row];
        int end = row_ptr[row + 1];
        float acc = 0.0f;
        int j = beg;
        for (; j + 1 < end; j += 2) {  // 2 outstanding row loads
            int i0 = eidx[j];
            int i1 = eidx[j + 1];
            acc += xsrc[(size_t)i0 * H + t];
            acc += xsrc[(size_t)i1 * H + t];
        }
        if (j < end) acc += xsrc[(size_t)eidx[j] * H + t];
        aS[r][t] = acc * (1.0f / fmaxf((float)(end - beg), 1.0f));
        xS[r][t] = xdst[(size_t)row * H + t];
    }
    __syncthreads();
    float acc[RT];
    float bb = b[t];
#pragma unroll
    for (int r = 0; r < RT; ++r) acc[r] = bb;
#pragma unroll 4
    for (int k = 0; k < H; ++k) {
        float wm = Wm[k * H + t];
        float ws = Ws[k * H + t];
#pragma unroll
        for (int r = 0; r < RT; ++r) acc[r] += aS[r][k] * wm + xS[r][k] * ws;
    }
#pragma unroll
    for (int r = 0; r < RT; ++r) {
        float v = acc[r];
        if (RELU) v = fmaxf(v, 0.0f);
        out[(size_t)(row0 + r) * H + t] = v;
    }
}

// ---------------------------------------------------------------------------
// Head: pred[e] = dot(xu2[el_src[e],:], xa2[el_dst[e],:])  (one wave per pair)
// ---------------------------------------------------------------------------
__global__ __launch_bounds__(256)
void pred_kernel(const float* __restrict__ xu,  // [NU,H]
                 const float* __restrict__ xa,  // [NA,H]
                 const int* __restrict__ esrc,  // [EL]
                 const int* __restrict__ edst,  // [EL]
                 float* __restrict__ out,       // [EL]
                 int E) {
    long long idx = (long long)blockIdx.x * blockDim.x + threadIdx.x;
    int e = (int)(idx >> 6);
    if (e >= E) return;
    int l = (int)(idx & 63);
    int s = esrc[e];
    int d = edst[e];
    const float* pu = xu + (size_t)s * H;
    const float* pa = xa + (size_t)d * H;
    float v = pu[l] * pa[l] + pu[l + 64] * pa[l + 64];
#pragma unroll
    for (int off = 32; off > 0; off >>= 1) v += __shfl_down(v, off);
    if (l == 0) out[e] = v;
}

// ---------------------------------------------------------------------------
extern "C" void kernel_launch(void* const* d_in, const int* in_sizes, int n_in,
                              void* d_out, int out_size, void* d_ws, size_t ws_size,
                              hipStream_t stream) {
    const float* user_x     = (const float*)d_in[0];
    const float* app_x      = (const float*)d_in[1];
    const float* user_emb   = (const float*)d_in[2];
    const float* app_emb    = (const float*)d_in[3];
    const float* user_lin_W = (const float*)d_in[4];
    const float* user_lin_b = (const float*)d_in[5];
    const float* app_lin_W  = (const float*)d_in[6];
    const float* app_lin_b  = (const float*)d_in[7];
    const float* W_msg_ua1  = (const float*)d_in[8];
    const float* W_self_ua1 = (const float*)d_in[9];
    const float* b_ua1      = (const float*)d_in[10];
    const float* W_msg_au1  = (const float*)d_in[11];
    const float* W_self_au1 = (const float*)d_in[12];
    const float* b_au1      = (const float*)d_in[13];
    const float* W_msg_ua2  = (const float*)d_in[14];
    const float* W_self_ua2 = (const float*)d_in[15];
    const float* b_ua2      = (const float*)d_in[16];
    const float* W_msg_au2  = (const float*)d_in[17];
    const float* W_self_au2 = (const float*)d_in[18];
    const float* b_au2      = (const float*)d_in[19];
    const int*   user_n_id  = (const int*)d_in[20];
    const int*   app_n_id   = (const int*)d_in[21];
    const int*   e_src_u2a  = (const int*)d_in[22];
    const int*   e_dst_u2a  = (const int*)d_in[23];
    const int*   e_src_a2u  = (const int*)d_in[24];
    const int*   e_dst_a2u  = (const int*)d_in[25];
    const int*   el_src     = (const int*)d_in[26];
    const int*   el_dst     = (const int*)d_in[27];
    float* pred = (float*)d_out;
    (void)in_sizes; (void)n_in; (void)out_size; (void)ws_size;

    // ---- workspace layout ----
    char* p = (char*)d_ws;
    auto alloc = [&](size_t bytes) {
        char* r = p;
        p += (bytes + 255) & ~(size_t)255;
        return (void*)r;
    };
    float* XU0 = (float*)alloc((size_t)NU * H * 4);  // xu0, later xu2
    float* XU1 = (float*)alloc((size_t)NU * H * 4);
    float* XA0 = (float*)alloc((size_t)NA * H * 4);  // xa0, later xa2
    float* XA1 = (float*)alloc((size_t)NA * H * 4);
    int* eidx_ua = (int*)alloc((size_t)NE * 4);      // u2a: src users, dst-sorted by app
    int* eidx_au = (int*)alloc((size_t)NE * 4);      // a2u: src apps, dst-sorted by user
    int* rp_a    = (int*)alloc((size_t)(NA + 1) * 4);
    int* rp_u    = (int*)alloc((size_t)(NU + 1) * 4);
    int* deg_u   = (int*)alloc((size_t)NU * 4);      // reused as fill counters
    int* deg_a   = (int*)alloc((size_t)NA * 4);
    int* incl    = (int*)alloc((size_t)NU * 4);      // scan temp (max N)
    int* bsum    = (int*)alloc((size_t)1024 * 4);

    const int egrid  = (NE + 255) / 256;
    const int pgrid  = (int)(((long long)NEL * 64 + 255) / 256);
    const int nb_u   = (NU + 1023) / 1024;
    const int nb_a   = (NA + 1023) / 1024;

    // ---- prologue (independent of CSR) ----
    prologue_kernel<FU><<<NU, 128, 0, stream>>>(user_x, user_emb, user_lin_W,
                                                user_lin_b, user_n_id, XU0, NU);
    prologue_kernel<FA><<<NA, 128, 0, stream>>>(app_x, app_emb, app_lin_W,
                                                app_lin_b, app_n_id, XA0, NA);

    // ---- CSR u2a (dst = apps) ----
    hipMemsetAsync(deg_a, 0, (size_t)NA * 4, stream);
    hist_kernel<<<egrid, 256, 0, stream>>>(e_dst_u2a, deg_a, NE);
    scan1_kernel<<<nb_a, 1024, 0, stream>>>(deg_a, incl, bsum, NA);
    scan2_kernel<<<1, 1024, 0, stream>>>(bsum, nb_a);
    scan3_kernel<<<(NA + 255) / 256, 256, 0, stream>>>(incl, bsum, rp_a, NA);
    hipMemsetAsync(deg_a, 0, (size_t)NA * 4, stream);
    fill_kernel<<<egrid, 256, 0, stream>>>(e_src_u2a, e_dst_u2a, rp_a, deg_a,
                                           eidx_ua, NE);

    // ---- CSR a2u (dst = users) ----
    hipMemsetAsync(deg_u, 0, (size_t)NU * 4, stream);
    hist_kernel<<<egrid, 256, 0, stream>>>(e_dst_a2u, deg_u, NE);
    scan1_kernel<<<nb_u, 1024, 0, stream>>>(deg_u, incl, bsum, NU);
    scan2_kernel<<<1, 1024, 0, stream>>>(bsum, nb_u);
    scan3_kernel<<<(NU + 255) / 256, 256, 0, stream>>>(incl, bsum, rp_u, NU);
    hipMemsetAsync(deg_u, 0, (size_t)NU * 4, stream);
    fill_kernel<<<egrid, 256, 0, stream>>>(e_src_a2u, e_dst_a2u, rp_u, deg_u,
                                           eidx_au, NE);

    // ---- layer 1 ----
    // xa1 = relu(mean_{u->a}(xu0) @ Wm + xa0 @ Ws + b)
    sage_fused<true, 16><<<NA / 16, 128, 0, stream>>>(XU0, rp_a, eidx_ua, XA0,
                                                      W_msg_ua1, W_self_ua1,
                                                      b_ua1, XA1, NA);
    // xu1 = relu(mean_{a->u}(xa0) @ Wm + xu0 @ Ws + b)
    sage_fused<true, 16><<<NU / 16, 128, 0, stream>>>(XA0, rp_u, eidx_au, XU0,
                                                      W_msg_au1, W_self_au1,
                                                      b_au1, XU1, NU);

    // ---- layer 2 (outputs overwrite the dead layer-0 buffers) ----
    // xa2 = mean_{u->a}(xu1) @ Wm + xa1 @ Ws + b   (into XA0)
    sage_fused<false, 16><<<NA / 16, 128, 0, stream>>>(XU1, rp_a, eidx_ua, XA1,
                                                       W_msg_ua2, W_self_ua2,
                                                       b_ua2, XA0, NA);
    // xu2 = mean_{a->u}(xa1) @ Wm + xu1 @ Ws + b   (into XU0)
    sage_fused<false, 16><<<NU / 16, 128, 0, stream>>>(XA1, rp_u, eidx_au, XU1,
                                                       W_msg_au2, W_self_au2,
                                                       b_au2, XU0, NU);

    // ---- head ----
    pred_kernel<<<pgrid, 256, 0, stream>>>(XU0, XA0, el_src, el_dst, pred, NEL);
}

// Round 3
// 768.421 us; speedup vs baseline: 9.8374x; 1.7739x over previous
//
#include <hip/hip_runtime.h>
#include <hip/hip_bf16.h>

// Problem constants (match reference setup_inputs)
constexpr int NU  = 100000;   // users
constexpr int NA  = 20000;    // apps
constexpr int FU  = 32;
constexpr int FA  = 64;
constexpr int H   = 128;
constexpr int NE  = 1000000;  // edges per direction
constexpr int NEL = 500000;   // labeled pairs

using bf16x8 = __attribute__((ext_vector_type(8))) short;
using f32x4  = __attribute__((ext_vector_type(4))) float;

__device__ inline unsigned short f2bf(float f) {
    union { float f; unsigned u; } x; x.f = f;
    unsigned u = x.u;
    return (unsigned short)((u + 0x7fffu + ((u >> 16) & 1u)) >> 16);  // RNE
}
__device__ inline float bf2f(unsigned short s) {
    union { unsigned u; float f; } x; x.u = ((unsigned)s) << 16;
    return x.f;
}

// ---------------------------------------------------------------------------
// Prologue: out[i,:] = emb[nid[i],:] + x[i,:] @ W + b   (one row per block)
// ---------------------------------------------------------------------------
template <int F>
__global__ __launch_bounds__(128)
void prologue_kernel(const float* __restrict__ x, const float* __restrict__ emb,
                     const float* __restrict__ W, const float* __restrict__ b,
                     const int* __restrict__ nid, float* __restrict__ out, int N) {
    __shared__ float xs[F];
    int row = blockIdx.x;
    if (row >= N) return;
    int t = threadIdx.x;  // output column
    if (t < F) xs[t] = x[(size_t)row * F + t];
    __syncthreads();
    int id = nid[row];
    float acc = emb[(size_t)id * H + t] + b[t];
#pragma unroll
    for (int k = 0; k < F; ++k) acc += xs[k] * W[k * H + t];
    out[(size_t)row * H + t] = acc;
}

// ---------------------------------------------------------------------------
// CSR build: histogram -> scan -> fill
// ---------------------------------------------------------------------------
__global__ __launch_bounds__(256)
void hist_kernel(const int* __restrict__ edst, int* __restrict__ deg, int E) {
    int e = blockIdx.x * blockDim.x + threadIdx.x;
    if (e < E) atomicAdd(&deg[edst[e]], 1);
}

__global__ __launch_bounds__(1024)
void scan1_kernel(const int* __restrict__ deg, int* __restrict__ incl,
                  int* __restrict__ bsum, int N) {
    __shared__ int s[1024];
    int t = threadIdx.x;
    int i = blockIdx.x * 1024 + t;
    s[t] = (i < N) ? deg[i] : 0;
    __syncthreads();
    for (int d = 1; d < 1024; d <<= 1) {
        int add = (t >= d) ? s[t - d] : 0;
        __syncthreads();
        s[t] += add;
        __syncthreads();
    }
    if (i < N) incl[i] = s[t];
    if (t == 1023) bsum[blockIdx.x] = s[1023];
}

__global__ __launch_bounds__(1024)
void scan2_kernel(int* __restrict__ bsum, int nb) {
    __shared__ int s[1024];
    int t = threadIdx.x;
    s[t] = (t < nb) ? bsum[t] : 0;
    __syncthreads();
    for (int d = 1; d < 1024; d <<= 1) {
        int add = (t >= d) ? s[t - d] : 0;
        __syncthreads();
        s[t] += add;
        __syncthreads();
    }
    if (t < nb) bsum[t] = s[t];
}

__global__ __launch_bounds__(256)
void scan3_kernel(const int* __restrict__ incl, const int* __restrict__ bsum,
                  int* __restrict__ row_ptr, int N) {
    int i = blockIdx.x * 256 + threadIdx.x;
    if (i == 0) row_ptr[0] = 0;
    if (i < N) {
        int blk = i >> 10;
        int off = (blk > 0) ? bsum[blk - 1] : 0;
        row_ptr[i + 1] = incl[i] + off;
    }
}

__global__ __launch_bounds__(256)
void fill_kernel(const int* __restrict__ esrc, const int* __restrict__ edst,
                 const int* __restrict__ row_ptr, int* __restrict__ fill,
                 int* __restrict__ eidx, int E) {
    int e = blockIdx.x * blockDim.x + threadIdx.x;
    if (e >= E) return;
    int d = edst[e];
    int pos = row_ptr[d] + atomicAdd(&fill[d], 1);
    eidx[pos] = esrc[e];
}

// ---------------------------------------------------------------------------
// Weight pack: Bp fragment-ordered bf16, element ((n*4+ks)*64+l)*8+j holds
// W[k = ks*32+(l>>4)*8+j][n_global = n*16+(l&15)], W = [Wmsg | Wself] (128x256).
// Any bijective k->slot map works as long as A uses the same one.
// ---------------------------------------------------------------------------
__global__ __launch_bounds__(256)
void pack_kernel(const float* __restrict__ Wm, const float* __restrict__ Ws,
                 unsigned short* __restrict__ Bp) {
    int idx = blockIdx.x * 256 + threadIdx.x;  // 0..32767
    if (idx >= 32768) return;
    int j = idx & 7, l = (idx >> 3) & 63, ks = (idx >> 9) & 3, n = idx >> 11;
    int ng = n * 16 + (l & 15);
    int kg = ks * 32 + (l >> 4) * 8 + j;
    float v = (n < 8) ? Wm[kg * H + ng] : Ws[kg * H + (ng - 128)];
    Bp[idx] = f2bf(v);
}

// ---------------------------------------------------------------------------
// Dense GEMM: [Msg | Self] = A @ [Wmsg | Wself], M x 128 x 256, bf16 MFMA.
// Msg stored bf16, Self stored f32. Self MAY ALIAS A (in-place): each block
// reads only its own 128 rows of A and writes the same rows, all A loads
// precede all stores via the accumulator dependency.
// Block = 256 thr (4 waves), BM=128 (wave: 2 m-tiles of 16 rows), full N=256.
// ---------------------------------------------------------------------------
__global__ __launch_bounds__(256)
void gemm_msg_self(const float* A, const unsigned short* __restrict__ Bp,
                   unsigned short* __restrict__ Msg, float* Self, int M) {
    __shared__ unsigned short Bs[32768];  // 64 KB packed weights
    int tid = threadIdx.x;
    {
        const int4* s = (const int4*)Bp;
        int4* d = (int4*)Bs;
#pragma unroll
        for (int i = 0; i < 16; ++i) d[tid + 256 * i] = s[tid + 256 * i];
    }
    __syncthreads();
    const int w = tid >> 6, l = tid & 63;
    const int l16 = l & 15, lg = l >> 4;
    const int r0 = blockIdx.x * 128 + w * 32;
    const int ra0 = min(r0 + l16, M - 1);       // A row, m-tile 0
    const int ra1 = min(r0 + 16 + l16, M - 1);  // A row, m-tile 1
    f32x4 acc0[16], acc1[16];
#pragma unroll
    for (int n = 0; n < 16; ++n) {
        acc0[n] = f32x4{0.f, 0.f, 0.f, 0.f};
        acc1[n] = f32x4{0.f, 0.f, 0.f, 0.f};
    }
#pragma unroll
    for (int ks = 0; ks < 4; ++ks) {
        const float* pa0 = A + (size_t)ra0 * H + ks * 32 + lg * 8;
        const float* pa1 = A + (size_t)ra1 * H + ks * 32 + lg * 8;
        float4 u0 = *(const float4*)pa0, u1 = *(const float4*)(pa0 + 4);
        float4 v0 = *(const float4*)pa1, v1 = *(const float4*)(pa1 + 4);
        bf16x8 a0, a1;
        a0[0] = f2bf(u0.x); a0[1] = f2bf(u0.y); a0[2] = f2bf(u0.z); a0[3] = f2bf(u0.w);
        a0[4] = f2bf(u1.x); a0[5] = f2bf(u1.y); a0[6] = f2bf(u1.z); a0[7] = f2bf(u1.w);
        a1[0] = f2bf(v0.x); a1[1] = f2bf(v0.y); a1[2] = f2bf(v0.z); a1[3] = f2bf(v0.w);
        a1[4] = f2bf(v1.x); a1[5] = f2bf(v1.y); a1[6] = f2bf(v1.z); a1[7] = f2bf(v1.w);
#pragma unroll
        for (int n = 0; n < 16; ++n) {
            bf16x8 bf = *(const bf16x8*)&Bs[((n * 4 + ks) * 64 + l) * 8];
            acc0[n] = __builtin_amdgcn_mfma_f32_16x16x32_bf16(a0, bf, acc0[n], 0, 0, 0);
            acc1[n] = __builtin_amdgcn_mfma_f32_16x16x32_bf16(a1, bf, acc1[n], 0, 0, 0);
        }
    }
    // C/D layout (m89-verified): col = lane&15, row = (lane>>4)*4 + j
#pragma unroll
    for (int n = 0; n < 16; ++n) {
#pragma unroll
        for (int j = 0; j < 4; ++j) {
            int rr0 = r0 + lg * 4 + j;
            int rr1 = rr0 + 16;
            if (n < 8) {
                int c = n * 16 + l16;
                if (rr0 < M) Msg[(size_t)rr0 * H + c] = f2bf(acc0[n][j]);
                if (rr1 < M) Msg[(size_t)rr1 * H + c] = f2bf(acc1[n][j]);
            } else {
                int c = (n - 8) * 16 + l16;
                if (rr0 < M) Self[(size_t)rr0 * H + c] = acc0[n][j];
                if (rr1 < M) Self[(size_t)rr1 * H + c] = acc1[n][j];
            }
        }
    }
}

// ---------------------------------------------------------------------------
// Aggregate + finish: out[i,:] = [relu]( mean_j Msg[eidx[j],:] + Self[i,:] + b )
// One wave per dst row; lane handles cols {2l, 2l+1} (dword bf16x2 gathers).
// ---------------------------------------------------------------------------
template <bool RELU>
__global__ __launch_bounds__(256)
void agg_finish(const unsigned short* __restrict__ Msg,  // [Nsrc,H] bf16
                const int* __restrict__ rp, const int* __restrict__ eidx,
                const float* __restrict__ Self,          // [N,H] f32
                const float* __restrict__ b,             // [H]
                float* __restrict__ out,                 // [N,H] f32
                int N) {
    int w = threadIdx.x >> 6, l = threadIdx.x & 63;
    int row = blockIdx.x * 4 + w;
    if (row >= N) return;
    int beg = rp[row], end = rp[row + 1];
    float s = 1.0f / fmaxf((float)(end - beg), 1.0f);
    float a0 = 0.f, a1 = 0.f;
    int j = beg;
    for (; j + 1 < end; j += 2) {
        int s0 = eidx[j], s1 = eidx[j + 1];
        unsigned m0 = *(const unsigned*)(Msg + (size_t)s0 * H + 2 * l);
        unsigned m1 = *(const unsigned*)(Msg + (size_t)s1 * H + 2 * l);
        a0 += bf2f((unsigned short)(m0 & 0xffff)) + bf2f((unsigned short)(m1 & 0xffff));
        a1 += bf2f((unsigned short)(m0 >> 16)) + bf2f((unsigned short)(m1 >> 16));
    }
    if (j < end) {
        unsigned m0 = *(const unsigned*)(Msg + (size_t)eidx[j] * H + 2 * l);
        a0 += bf2f((unsigned short)(m0 & 0xffff));
        a1 += bf2f((unsigned short)(m0 >> 16));
    }
    float2 sf = *(const float2*)(Self + (size_t)row * H + 2 * l);
    float2 bb = *(const float2*)(b + 2 * l);
    float o0 = a0 * s + sf.x + bb.x;
    float o1 = a1 * s + sf.y + bb.y;
    if (RELU) { o0 = fmaxf(o0, 0.f); o1 = fmaxf(o1, 0.f); }
    *(float2*)(out + (size_t)row * H + 2 * l) = make_float2(o0, o1);
}

// ---------------------------------------------------------------------------
// Head: pred[e] = dot(xu2[el_src[e],:], xa2[el_dst[e],:])  (one wave per pair)
// ---------------------------------------------------------------------------
__global__ __launch_bounds__(256)
void pred_kernel(const float* __restrict__ xu, const float* __restrict__ xa,
                 const int* __restrict__ esrc, const int* __restrict__ edst,
                 float* __restrict__ out, int E) {
    long long idx = (long long)blockIdx.x * blockDim.x + threadIdx.x;
    int e = (int)(idx >> 6);
    if (e >= E) return;
    int l = (int)(idx & 63);
    int s = esrc[e];
    int d = edst[e];
    float2 u = *(const float2*)(xu + (size_t)s * H + 2 * l);
    float2 a = *(const float2*)(xa + (size_t)d * H + 2 * l);
    float v = u.x * a.x + u.y * a.y;
#pragma unroll
    for (int off = 32; off > 0; off >>= 1) v += __shfl_down(v, off);
    if (l == 0) out[e] = v;
}

// ---------------------------------------------------------------------------
extern "C" void kernel_launch(void* const* d_in, const int* in_sizes, int n_in,
                              void* d_out, int out_size, void* d_ws, size_t ws_size,
                              hipStream_t stream) {
    const float* user_x     = (const float*)d_in[0];
    const float* app_x      = (const float*)d_in[1];
    const float* user_emb   = (const float*)d_in[2];
    const float* app_emb    = (const float*)d_in[3];
    const float* user_lin_W = (const float*)d_in[4];
    const float* user_lin_b = (const float*)d_in[5];
    const float* app_lin_W  = (const float*)d_in[6];
    const float* app_lin_b  = (const float*)d_in[7];
    const float* W_msg_ua1  = (const float*)d_in[8];
    const float* W_self_ua1 = (const float*)d_in[9];
    const float* b_ua1      = (const float*)d_in[10];
    const float* W_msg_au1  = (const float*)d_in[11];
    const float* W_self_au1 = (const float*)d_in[12];
    const float* b_au1      = (const float*)d_in[13];
    const float* W_msg_ua2  = (const float*)d_in[14];
    const float* W_self_ua2 = (const float*)d_in[15];
    const float* b_ua2      = (const float*)d_in[16];
    const float* W_msg_au2  = (const float*)d_in[17];
    const float* W_self_au2 = (const float*)d_in[18];
    const float* b_au2      = (const float*)d_in[19];
    const int*   user_n_id  = (const int*)d_in[20];
    const int*   app_n_id   = (const int*)d_in[21];
    const int*   e_src_u2a  = (const int*)d_in[22];
    const int*   e_dst_u2a  = (const int*)d_in[23];
    const int*   e_src_a2u  = (const int*)d_in[24];
    const int*   e_dst_a2u  = (const int*)d_in[25];
    const int*   el_src     = (const int*)d_in[26];
    const int*   el_dst     = (const int*)d_in[27];
    float* pred = (float*)d_out;
    (void)in_sizes; (void)n_in; (void)out_size; (void)ws_size;

    // ---- workspace layout (~164 MB; round-1 layout proved >=185 MB exists) ----
    char* p = (char*)d_ws;
    auto alloc = [&](size_t bytes) {
        char* r = p;
        p += (bytes + 255) & ~(size_t)255;
        return (void*)r;
    };
    float* XU0 = (float*)alloc((size_t)NU * H * 4);   // xu0 -> Self_u (in-place) -> xu2
    float* XU1 = (float*)alloc((size_t)NU * H * 4);   // xu1 -> Self_u L2 (in-place)
    float* XA0 = (float*)alloc((size_t)NA * H * 4);   // xa0 -> Self_a -> xa2
    float* XA1 = (float*)alloc((size_t)NA * H * 4);   // xa1 -> Self_a L2
    unsigned short* MSGU = (unsigned short*)alloc((size_t)NU * H * 2);  // bf16
    unsigned short* MSGA = (unsigned short*)alloc((size_t)NA * H * 2);  // bf16
    int* eidx_ua = (int*)alloc((size_t)NE * 4);
    int* eidx_au = (int*)alloc((size_t)NE * 4);
    int* rp_a    = (int*)alloc((size_t)(NA + 1) * 4);
    int* rp_u    = (int*)alloc((size_t)(NU + 1) * 4);
    int* deg_u   = (int*)alloc((size_t)NU * 4);
    int* deg_a   = (int*)alloc((size_t)NA * 4);
    int* incl    = (int*)alloc((size_t)NU * 4);
    int* bsum    = (int*)alloc((size_t)1024 * 4);
    unsigned short* Bp_u1 = (unsigned short*)alloc(32768 * 2);
    unsigned short* Bp_a1 = (unsigned short*)alloc(32768 * 2);
    unsigned short* Bp_u2 = (unsigned short*)alloc(32768 * 2);
    unsigned short* Bp_a2 = (unsigned short*)alloc(32768 * 2);

    const int egrid = (NE + 255) / 256;
    const int pgrid = (int)(((long long)NEL * 64 + 255) / 256);
    const int nb_u  = (NU + 1023) / 1024;
    const int nb_a  = (NA + 1023) / 1024;
    const int gg_u  = (NU + 127) / 128;
    const int gg_a  = (NA + 127) / 128;

    // ---- prologue ----
    prologue_kernel<FU><<<NU, 128, 0, stream>>>(user_x, user_emb, user_lin_W,
                                                user_lin_b, user_n_id, XU0, NU);
    prologue_kernel<FA><<<NA, 128, 0, stream>>>(app_x, app_emb, app_lin_W,
                                                app_lin_b, app_n_id, XA0, NA);

    // ---- weight packs (user pack: [W_msg_ua | W_self_au]; app: [W_msg_au | W_self_ua]) ----
    pack_kernel<<<128, 256, 0, stream>>>(W_msg_ua1, W_self_au1, Bp_u1);
    pack_kernel<<<128, 256, 0, stream>>>(W_msg_au1, W_self_ua1, Bp_a1);
    pack_kernel<<<128, 256, 0, stream>>>(W_msg_ua2, W_self_au2, Bp_u2);
    pack_kernel<<<128, 256, 0, stream>>>(W_msg_au2, W_self_ua2, Bp_a2);

    // ---- CSR u2a (dst = apps) ----
    hipMemsetAsync(deg_a, 0, (size_t)NA * 4, stream);
    hist_kernel<<<egrid, 256, 0, stream>>>(e_dst_u2a, deg_a, NE);
    scan1_kernel<<<nb_a, 1024, 0, stream>>>(deg_a, incl, bsum, NA);
    scan2_kernel<<<1, 1024, 0, stream>>>(bsum, nb_a);
    scan3_kernel<<<(NA + 255) / 256, 256, 0, stream>>>(incl, bsum, rp_a, NA);
    hipMemsetAsync(deg_a, 0, (size_t)NA * 4, stream);
    fill_kernel<<<egrid, 256, 0, stream>>>(e_src_u2a, e_dst_u2a, rp_a, deg_a,
                                           eidx_ua, NE);

    // ---- CSR a2u (dst = users) ----
    hipMemsetAsync(deg_u, 0, (size_t)NU * 4, stream);
    hist_kernel<<<egrid, 256, 0, stream>>>(e_dst_a2u, deg_u, NE);
    scan1_kernel<<<nb_u, 1024, 0, stream>>>(deg_u, incl, bsum, NU);
    scan2_kernel<<<1, 1024, 0, stream>>>(bsum, nb_u);
    scan3_kernel<<<(NU + 255) / 256, 256, 0, stream>>>(incl, bsum, rp_u, NU);
    hipMemsetAsync(deg_u, 0, (size_t)NU * 4, stream);
    fill_kernel<<<egrid, 256, 0, stream>>>(e_src_a2u, e_dst_a2u, rp_u, deg_u,
                                           eidx_au, NE);

    // ---- layer 1 GEMMs (Self written in-place over dead layer-0 features) ----
    gemm_msg_self<<<gg_u, 256, 0, stream>>>(XU0, Bp_u1, MSGU, XU0, NU);
    gemm_msg_self<<<gg_a, 256, 0, stream>>>(XA0, Bp_a1, MSGA, XA0, NA);

    // ---- layer 1 aggregate+finish ----
    // xa1 = relu(mean_{u2a}(MSGU) + Self_a(XA0) + b_ua1)
    agg_finish<true><<<(NA + 3) / 4, 256, 0, stream>>>(MSGU, rp_a, eidx_ua,
                                                       XA0, b_ua1, XA1, NA);
    // xu1 = relu(mean_{a2u}(MSGA) + Self_u(XU0) + b_au1)
    agg_finish<true><<<(NU + 3) / 4, 256, 0, stream>>>(MSGA, rp_u, eidx_au,
                                                       XU0, b_au1, XU1, NU);

    // ---- layer 2 GEMMs ----
    gemm_msg_self<<<gg_u, 256, 0, stream>>>(XU1, Bp_u2, MSGU, XU1, NU);
    gemm_msg_self<<<gg_a, 256, 0, stream>>>(XA1, Bp_a2, MSGA, XA1, NA);

    // ---- layer 2 aggregate+finish (no relu) ----
    // xa2 = mean_{u2a}(MSGU) + Self_a(XA1) + b_ua2  -> XA0
    agg_finish<false><<<(NA + 3) / 4, 256, 0, stream>>>(MSGU, rp_a, eidx_ua,
                                                        XA1, b_ua2, XA0, NA);
    // xu2 = mean_{a2u}(MSGA) + Self_u(XU1) + b_au2  -> XU0
    agg_finish<false><<<(NU + 3) / 4, 256, 0, stream>>>(MSGA, rp_u, eidx_au,
                                                        XU1, b_au2, XU0, NU);

    // ---- head ----
    pred_kernel<<<pgrid, 256, 0, stream>>>(XU0, XA0, el_src, el_dst, pred, NEL);
}

// Round 4
// 735.781 us; speedup vs baseline: 10.2738x; 1.0444x over previous
//
#include <hip/hip_runtime.h>

// Problem constants (match reference setup_inputs)
constexpr int NU  = 100000;   // users
constexpr int NA  = 20000;    // apps
constexpr int FU  = 32;
constexpr int FA  = 64;
constexpr int H   = 128;
constexpr int NE  = 1000000;  // edges per direction
constexpr int NEL = 500000;   // labeled pairs

constexpr int G_E  = (NE + 255) / 256;    // 3907 blocks per 1M-edge list
constexpr int G_EL = (NEL + 255) / 256;   // 1954
constexpr int NB_A = (NA + 1023) / 1024;  // 20
constexpr int NB_U = (NU + 1023) / 1024;  // 98
constexpr int NTOT = NA + NU + NA;        // deg/cur/incl layout: [a | u | el]

using bf16x8 = __attribute__((ext_vector_type(8))) short;
using f32x4  = __attribute__((ext_vector_type(4))) float;

__device__ inline unsigned short f2bf(float f) {
    union { float f; unsigned u; } x; x.f = f;
    unsigned u = x.u;
    return (unsigned short)((u + 0x7fffu + ((u >> 16) & 1u)) >> 16);  // RNE
}
__device__ inline float bf2f(unsigned short s) {
    union { unsigned u; float f; } x; x.u = ((unsigned)s) << 16;
    return x.f;
}

// ---------------------------------------------------------------------------
// Prologue: out[i,:] = bf16( emb[nid[i],:] + x[i,:] @ W + b )  (1 row / block)
// bf16 store is error-free vs the old path: the GEMM converted A to bf16
// in-register anyway.
// ---------------------------------------------------------------------------
template <int F>
__global__ __launch_bounds__(128)
void prologue_kernel(const float* __restrict__ x, const float* __restrict__ emb,
                     const float* __restrict__ W, const float* __restrict__ b,
                     const int* __restrict__ nid, unsigned short* __restrict__ out,
                     int N) {
    __shared__ float xs[F];
    int row = blockIdx.x;
    if (row >= N) return;
    int t = threadIdx.x;  // output column
    if (t < F) xs[t] = x[(size_t)row * F + t];
    __syncthreads();
    int id = nid[row];
    float acc = emb[(size_t)id * H + t] + b[t];
#pragma unroll
    for (int k = 0; k < F; ++k) acc += xs[k] * W[k * H + t];
    out[(size_t)row * H + t] = f2bf(acc);
}

// ---------------------------------------------------------------------------
// Merged CSR build over 3 graphs: u2a (dst=apps), a2u (dst=users), el (dst=apps)
// deg/cur layout bases: a=0, u=NA, el=NA+NU.  bsum bases: 0, 32, 160.
// rp bases: a=0 (NA+1), u=NA+1 (NU+1), el=NA+NU+2 (NA+1).
// ---------------------------------------------------------------------------
__global__ __launch_bounds__(256)
void hist_all(const int* __restrict__ d1, const int* __restrict__ d2,
              const int* __restrict__ d3, int* __restrict__ deg) {
    int b = blockIdx.x;
    if (b < G_E) {
        int e = b * 256 + threadIdx.x;
        if (e < NE) atomicAdd(&deg[d1[e]], 1);
    } else if (b < 2 * G_E) {
        int e = (b - G_E) * 256 + threadIdx.x;
        if (e < NE) atomicAdd(&deg[NA + d2[e]], 1);
    } else {
        int e = (b - 2 * G_E) * 256 + threadIdx.x;
        if (e < NEL) atomicAdd(&deg[NA + NU + d3[e]], 1);
    }
}

__global__ __launch_bounds__(1024)
void scan1_all(const int* __restrict__ deg, int* __restrict__ incl,
               int* __restrict__ bsum) {
    int b = blockIdx.x, t = threadIdx.x;
    int lb, n, base, bbase;
    if (b < NB_A)             { lb = b;              n = NA; base = 0;       bbase = 0;   }
    else if (b < NB_A + NB_U) { lb = b - NB_A;       n = NU; base = NA;      bbase = 32;  }
    else                      { lb = b - NB_A - NB_U; n = NA; base = NA + NU; bbase = 160; }
    __shared__ int s[1024];
    int i = lb * 1024 + t;
    s[t] = (i < n) ? deg[base + i] : 0;
    __syncthreads();
    for (int d = 1; d < 1024; d <<= 1) {
        int add = (t >= d) ? s[t - d] : 0;
        __syncthreads();
        s[t] += add;
        __syncthreads();
    }
    if (i < n) incl[base + i] = s[t];
    if (t == 1023) bsum[bbase + lb] = s[1023];
}

__global__ __launch_bounds__(1024)
void scan2_all(int* __restrict__ bsum) {
    int b = blockIdx.x, t = threadIdx.x;
    int nb, bbase;
    if (b == 0)      { nb = NB_A; bbase = 0;   }
    else if (b == 1) { nb = NB_U; bbase = 32;  }
    else             { nb = NB_A; bbase = 160; }
    __shared__ int s[1024];
    s[t] = (t < nb) ? bsum[bbase + t] : 0;
    __syncthreads();
    for (int d = 1; d < 1024; d <<= 1) {
        int add = (t >= d) ? s[t - d] : 0;
        __syncthreads();
        s[t] += add;
        __syncthreads();
    }
    if (t < nb) bsum[bbase + t] = s[t];
}

// writes rp and initializes the fill cursors (cur[i] = rp[i]) — no memset
__global__ __launch_bounds__(256)
void scan3_all(const int* __restrict__ incl, const int* __restrict__ bsum,
               int* __restrict__ rp, int* __restrict__ cur) {
    int i = blockIdx.x * 256 + threadIdx.x;
    if (i >= NTOT) return;
    int li, n, base, bbase, rbase;
    if (i < NA)           { li = i;           n = NA; base = 0;       bbase = 0;   rbase = 0;          }
    else if (i < NA + NU) { li = i - NA;      n = NU; base = NA;      bbase = 32;  rbase = NA + 1;     }
    else                  { li = i - NA - NU; n = NA; base = NA + NU; bbase = 160; rbase = NA + NU + 2; }
    int blk = li >> 10;
    int v = incl[base + li] + ((blk > 0) ? bsum[bbase + blk - 1] : 0);
    rp[rbase + li + 1] = v;
    if (li + 1 < n) cur[base + li + 1] = v;
    if (li == 0) { rp[rbase] = 0; cur[base] = 0; }
}

__global__ __launch_bounds__(256)
void fill_all(const int* __restrict__ s1, const int* __restrict__ d1,
              const int* __restrict__ s2, const int* __restrict__ d2,
              const int* __restrict__ s3, const int* __restrict__ d3,
              int* __restrict__ cur, int* __restrict__ eidx_ua,
              int* __restrict__ eidx_au, int2* __restrict__ elp) {
    int b = blockIdx.x;
    if (b < G_E) {
        int e = b * 256 + threadIdx.x;
        if (e >= NE) return;
        int d = d1[e];
        int pos = atomicAdd(&cur[d], 1);
        eidx_ua[pos] = s1[e];
    } else if (b < 2 * G_E) {
        int e = (b - G_E) * 256 + threadIdx.x;
        if (e >= NE) return;
        int d = d2[e];
        int pos = atomicAdd(&cur[NA + d], 1);
        eidx_au[pos] = s2[e];
    } else {
        int e = (b - 2 * G_E) * 256 + threadIdx.x;
        if (e >= NEL) return;
        int d = d3[e];
        int pos = atomicAdd(&cur[NA + NU + d], 1);
        elp[pos] = make_int2(s3[e], e);
    }
}

// ---------------------------------------------------------------------------
// Weight pack (all 4 GEMMs in one launch): Bp[which] fragment-ordered bf16.
// element ((n*4+ks)*64+l)*8+j holds W[k=ks*32+(l>>4)*8+j][n*16+(l&15)],
// W = [Wmsg | Wself] (128 x 256).
// ---------------------------------------------------------------------------
__global__ __launch_bounds__(256)
void pack_all(const float* __restrict__ Wm0, const float* __restrict__ Ws0,
              const float* __restrict__ Wm1, const float* __restrict__ Ws1,
              const float* __restrict__ Wm2, const float* __restrict__ Ws2,
              const float* __restrict__ Wm3, const float* __restrict__ Ws3,
              unsigned short* __restrict__ Bp) {
    int idx = blockIdx.x * 256 + threadIdx.x;  // 0 .. 4*32768-1
    int which = idx >> 15, li = idx & 32767;
    const float *Wm, *Ws;
    if (which == 0)      { Wm = Wm0; Ws = Ws0; }
    else if (which == 1) { Wm = Wm1; Ws = Ws1; }
    else if (which == 2) { Wm = Wm2; Ws = Ws2; }
    else                 { Wm = Wm3; Ws = Ws3; }
    int j = li & 7, l = (li >> 3) & 63, ks = (li >> 9) & 3, n = li >> 11;
    int ng = n * 16 + (l & 15);
    int kg = ks * 32 + (l >> 4) * 8 + j;
    float v = (n < 8) ? Wm[kg * H + ng] : Ws[kg * H + (ng - 128)];
    Bp[idx] = f2bf(v);
}

// ---------------------------------------------------------------------------
// Dense GEMM: [Msg | Self] = A @ [Wmsg | Wself], M x 128 x 256, bf16 MFMA.
// A is bf16 (direct fragment loads). Msg stored bf16, Self stored f32.
// Block = 256 thr (4 waves), BM=128 (wave: 2 m-tiles of 16 rows), full N=256.
// ---------------------------------------------------------------------------
__global__ __launch_bounds__(256)
void gemm_msg_self(const unsigned short* __restrict__ A,
                   const unsigned short* __restrict__ Bp,
                   unsigned short* __restrict__ Msg, float* __restrict__ Self,
                   int M) {
    __shared__ unsigned short Bs[32768];  // 64 KB packed weights
    int tid = threadIdx.x;
    {
        const int4* s = (const int4*)Bp;
        int4* d = (int4*)Bs;
#pragma unroll
        for (int i = 0; i < 16; ++i) d[tid + 256 * i] = s[tid + 256 * i];
    }
    __syncthreads();
    const int w = tid >> 6, l = tid & 63;
    const int l16 = l & 15, lg = l >> 4;
    const int r0 = blockIdx.x * 128 + w * 32;
    const int ra0 = min(r0 + l16, M - 1);       // A row, m-tile 0
    const int ra1 = min(r0 + 16 + l16, M - 1);  // A row, m-tile 1
    f32x4 acc0[16], acc1[16];
#pragma unroll
    for (int n = 0; n < 16; ++n) {
        acc0[n] = f32x4{0.f, 0.f, 0.f, 0.f};
        acc1[n] = f32x4{0.f, 0.f, 0.f, 0.f};
    }
#pragma unroll
    for (int ks = 0; ks < 4; ++ks) {
        bf16x8 a0 = *(const bf16x8*)(A + (size_t)ra0 * H + ks * 32 + lg * 8);
        bf16x8 a1 = *(const bf16x8*)(A + (size_t)ra1 * H + ks * 32 + lg * 8);
#pragma unroll
        for (int n = 0; n < 16; ++n) {
            bf16x8 bf = *(const bf16x8*)&Bs[((n * 4 + ks) * 64 + l) * 8];
            acc0[n] = __builtin_amdgcn_mfma_f32_16x16x32_bf16(a0, bf, acc0[n], 0, 0, 0);
            acc1[n] = __builtin_amdgcn_mfma_f32_16x16x32_bf16(a1, bf, acc1[n], 0, 0, 0);
        }
    }
    // C/D layout (m89-verified): col = lane&15, row = (lane>>4)*4 + j
#pragma unroll
    for (int n = 0; n < 16; ++n) {
#pragma unroll
        for (int j = 0; j < 4; ++j) {
            int rr0 = r0 + lg * 4 + j;
            int rr1 = rr0 + 16;
            if (n < 8) {
                int c = n * 16 + l16;
                if (rr0 < M) Msg[(size_t)rr0 * H + c] = f2bf(acc0[n][j]);
                if (rr1 < M) Msg[(size_t)rr1 * H + c] = f2bf(acc1[n][j]);
            } else {
                int c = (n - 8) * 16 + l16;
                if (rr0 < M) Self[(size_t)rr0 * H + c] = acc0[n][j];
                if (rr1 < M) Self[(size_t)rr1 * H + c] = acc1[n][j];
            }
        }
    }
}

// ---------------------------------------------------------------------------
// Aggregate + finish: tmp = mean_j Msg[eidx[j],:] + Self[i,:] + b
//   OUTBF16: out = bf16(relu(tmp))  (layer-1 features, GEMM-A format)
//   else:    out = tmp  f32, MAY ALIAS Self (per-thread read-before-write)
// One wave per dst row; lane handles cols {2l, 2l+1}; 4-deep gather ILP.
// ---------------------------------------------------------------------------
template <bool RELU, bool OUTBF16>
__global__ __launch_bounds__(256)
void agg_finish(const unsigned short* __restrict__ Msg,  // [Nsrc,H] bf16
                const int* __restrict__ rp, const int* __restrict__ eidx,
                const float* Self,                       // [N,H] f32 (no restrict: may alias out)
                const float* __restrict__ b,             // [H]
                void* outp, int N) {
    int w = threadIdx.x >> 6, l = threadIdx.x & 63;
    int row = blockIdx.x * 4 + w;
    if (row >= N) return;
    int beg = rp[row], end = rp[row + 1];
    float s = 1.0f / fmaxf((float)(end - beg), 1.0f);
    float a0 = 0.f, a1 = 0.f;
    int j = beg;
    for (; j + 3 < end; j += 4) {
        unsigned m0 = *(const unsigned*)(Msg + (size_t)eidx[j] * H + 2 * l);
        unsigned m1 = *(const unsigned*)(Msg + (size_t)eidx[j + 1] * H + 2 * l);
        unsigned m2 = *(const unsigned*)(Msg + (size_t)eidx[j + 2] * H + 2 * l);
        unsigned m3 = *(const unsigned*)(Msg + (size_t)eidx[j + 3] * H + 2 * l);
        a0 += bf2f((unsigned short)(m0 & 0xffff)) + bf2f((unsigned short)(m1 & 0xffff)) +
              bf2f((unsigned short)(m2 & 0xffff)) + bf2f((unsigned short)(m3 & 0xffff));
        a1 += bf2f((unsigned short)(m0 >> 16)) + bf2f((unsigned short)(m1 >> 16)) +
              bf2f((unsigned short)(m2 >> 16)) + bf2f((unsigned short)(m3 >> 16));
    }
    for (; j < end; ++j) {
        unsigned m0 = *(const unsigned*)(Msg + (size_t)eidx[j] * H + 2 * l);
        a0 += bf2f((unsigned short)(m0 & 0xffff));
        a1 += bf2f((unsigned short)(m0 >> 16));
    }
    float2 sf = *(const float2*)(Self + (size_t)row * H + 2 * l);
    float2 bb = *(const float2*)(b + 2 * l);
    float o0 = a0 * s + sf.x + bb.x;
    float o1 = a1 * s + sf.y + bb.y;
    if (RELU) { o0 = fmaxf(o0, 0.f); o1 = fmaxf(o1, 0.f); }
    if (OUTBF16) {
        unsigned pack = (unsigned)f2bf(o0) | ((unsigned)f2bf(o1) << 16);
        ((unsigned*)outp)[(size_t)row * (H / 2) + l] = pack;
    } else {
        ((float2*)outp)[(size_t)row * (H / 2) + l] = make_float2(o0, o1);
    }
}

// ---------------------------------------------------------------------------
// Head via el-CSR: one wave per app; xa row held in registers, only user rows
// gathered. pred[orig_e] = dot(xu2[u], xa2[app]).  2-deep edge ILP.
// ---------------------------------------------------------------------------
__global__ __launch_bounds__(256)
void pred_csr(const float* __restrict__ xu, const float* __restrict__ xa,
              const int* __restrict__ rp_el, const int2* __restrict__ elp,
              float* __restrict__ out) {
    int w = threadIdx.x >> 6, l = threadIdx.x & 63;
    int app = blockIdx.x * 4 + w;
    if (app >= NA) return;
    float2 a = *(const float2*)(xa + (size_t)app * H + 2 * l);
    int beg = rp_el[app], end = rp_el[app + 1];
    int j = beg;
    for (; j + 1 < end; j += 2) {
        int2 p0 = elp[j];
        int2 p1 = elp[j + 1];
        float2 u0 = *(const float2*)(xu + (size_t)p0.x * H + 2 * l);
        float2 u1 = *(const float2*)(xu + (size_t)p1.x * H + 2 * l);
        float v0 = u0.x * a.x + u0.y * a.y;
        float v1 = u1.x * a.x + u1.y * a.y;
#pragma unroll
        for (int off = 32; off > 0; off >>= 1) {
            v0 += __shfl_down(v0, off);
            v1 += __shfl_down(v1, off);
        }
        if (l == 0) { out[p0.y] = v0; out[p1.y] = v1; }
    }
    if (j < end) {
        int2 p0 = elp[j];
        float2 u0 = *(const float2*)(xu + (size_t)p0.x * H + 2 * l);
        float v0 = u0.x * a.x + u0.y * a.y;
#pragma unroll
        for (int off = 32; off > 0; off >>= 1) v0 += __shfl_down(v0, off);
        if (l == 0) out[p0.y] = v0;
    }
}

// ---------------------------------------------------------------------------
extern "C" void kernel_launch(void* const* d_in, const int* in_sizes, int n_in,
                              void* d_out, int out_size, void* d_ws, size_t ws_size,
                              hipStream_t stream) {
    const float* user_x     = (const float*)d_in[0];
    const float* app_x      = (const float*)d_in[1];
    const float* user_emb   = (const float*)d_in[2];
    const float* app_emb    = (const float*)d_in[3];
    const float* user_lin_W = (const float*)d_in[4];
    const float* user_lin_b = (const float*)d_in[5];
    const float* app_lin_W  = (const float*)d_in[6];
    const float* app_lin_b  = (const float*)d_in[7];
    const float* W_msg_ua1  = (const float*)d_in[8];
    const float* W_self_ua1 = (const float*)d_in[9];
    const float* b_ua1      = (const float*)d_in[10];
    const float* W_msg_au1  = (const float*)d_in[11];
    const float* W_self_au1 = (const float*)d_in[12];
    const float* b_au1      = (const float*)d_in[13];
    const float* W_msg_ua2  = (const float*)d_in[14];
    const float* W_self_ua2 = (const float*)d_in[15];
    const float* b_ua2      = (const float*)d_in[16];
    const float* W_msg_au2  = (const float*)d_in[17];
    const float* W_self_au2 = (const float*)d_in[18];
    const float* b_au2      = (const float*)d_in[19];
    const int*   user_n_id  = (const int*)d_in[20];
    const int*   app_n_id   = (const int*)d_in[21];
    const int*   e_src_u2a  = (const int*)d_in[22];
    const int*   e_dst_u2a  = (const int*)d_in[23];
    const int*   e_src_a2u  = (const int*)d_in[24];
    const int*   e_dst_a2u  = (const int*)d_in[25];
    const int*   el_src     = (const int*)d_in[26];
    const int*   el_dst     = (const int*)d_in[27];
    float* pred = (float*)d_out;
    (void)in_sizes; (void)n_in; (void)out_size; (void)ws_size;

    // ---- workspace layout (~137 MB; round-1 proved >=185 MB exists) ----
    char* p = (char*)d_ws;
    auto alloc = [&](size_t bytes) {
        char* r = p;
        p += (bytes + 255) & ~(size_t)255;
        return (void*)r;
    };
    float* SFU = (float*)alloc((size_t)NU * H * 4);   // Self_u (L1,L2) -> xu2 in-place
    float* SFA = (float*)alloc((size_t)NA * H * 4);   // Self_a (L1,L2) -> xa2 in-place
    unsigned short* XBU = (unsigned short*)alloc((size_t)NU * H * 2);  // x0_u then x1_u (bf16)
    unsigned short* XBA = (unsigned short*)alloc((size_t)NA * H * 2);  // x0_a then x1_a (bf16)
    unsigned short* MSGU = (unsigned short*)alloc((size_t)NU * H * 2); // bf16
    unsigned short* MSGA = (unsigned short*)alloc((size_t)NA * H * 2); // bf16
    int*  eidx_ua = (int*)alloc((size_t)NE * 4);      // u2a src users, dst-sorted by app
    int*  eidx_au = (int*)alloc((size_t)NE * 4);      // a2u src apps, dst-sorted by user
    int2* elp     = (int2*)alloc((size_t)NEL * 8);    // (user, orig_e), sorted by app
    int*  RP   = (int*)alloc((size_t)(NTOT + 3) * 4); // [rp_a | rp_u | rp_el]
    int*  deg  = (int*)alloc((size_t)NTOT * 4);       // [deg_a | deg_u | deg_el] -> cursors
    int*  incl = (int*)alloc((size_t)NTOT * 4);
    int*  bsum = (int*)alloc((size_t)256 * 4);
    unsigned short* Bp = (unsigned short*)alloc((size_t)4 * 32768 * 2);

    int* rp_a  = RP;
    int* rp_u  = RP + NA + 1;
    int* rp_el = RP + NA + NU + 2;
    unsigned short* Bp_u1 = Bp;
    unsigned short* Bp_a1 = Bp + 32768;
    unsigned short* Bp_u2 = Bp + 2 * 32768;
    unsigned short* Bp_a2 = Bp + 3 * 32768;

    const int gg_u = (NU + 127) / 128;
    const int gg_a = (NA + 127) / 128;

    // ---- prologue (writes bf16 features) ----
    prologue_kernel<FU><<<NU, 128, 0, stream>>>(user_x, user_emb, user_lin_W,
                                                user_lin_b, user_n_id, XBU, NU);
    prologue_kernel<FA><<<NA, 128, 0, stream>>>(app_x, app_emb, app_lin_W,
                                                app_lin_b, app_n_id, XBA, NA);

    // ---- weight packs (user pack: [W_msg_ua | W_self_au]; app: [W_msg_au | W_self_ua]) ----
    pack_all<<<512, 256, 0, stream>>>(W_msg_ua1, W_self_au1, W_msg_au1, W_self_ua1,
                                      W_msg_ua2, W_self_au2, W_msg_au2, W_self_ua2, Bp);

    // ---- merged CSR build (u2a, a2u, el) ----
    hipMemsetAsync(deg, 0, (size_t)NTOT * 4, stream);
    hist_all<<<2 * G_E + G_EL, 256, 0, stream>>>(e_dst_u2a, e_dst_a2u, el_dst, deg);
    scan1_all<<<NB_A + NB_U + NB_A, 1024, 0, stream>>>(deg, incl, bsum);
    scan2_all<<<3, 1024, 0, stream>>>(bsum);
    scan3_all<<<(NTOT + 255) / 256, 256, 0, stream>>>(incl, bsum, RP, deg);  // deg -> cursors
    fill_all<<<2 * G_E + G_EL, 256, 0, stream>>>(e_src_u2a, e_dst_u2a,
                                                 e_src_a2u, e_dst_a2u,
                                                 el_src, el_dst, deg,
                                                 eidx_ua, eidx_au, elp);

    // ---- layer 1 GEMMs: [Msg1 | Self1] = x0 @ [Wmsg | Wself] ----
    gemm_msg_self<<<gg_u, 256, 0, stream>>>(XBU, Bp_u1, MSGU, SFU, NU);
    gemm_msg_self<<<gg_a, 256, 0, stream>>>(XBA, Bp_a1, MSGA, SFA, NA);

    // ---- layer 1 aggregate+finish -> bf16 x1 (overwrites dead x0) ----
    agg_finish<true, true><<<NA / 4, 256, 0, stream>>>(MSGU, rp_a, eidx_ua,
                                                       SFA, b_ua1, XBA, NA);
    agg_finish<true, true><<<NU / 4, 256, 0, stream>>>(MSGA, rp_u, eidx_au,
                                                       SFU, b_au1, XBU, NU);

    // ---- layer 2 GEMMs: [Msg2 | Self2] = x1 @ [Wmsg | Wself] ----
    gemm_msg_self<<<gg_u, 256, 0, stream>>>(XBU, Bp_u2, MSGU, SFU, NU);
    gemm_msg_self<<<gg_a, 256, 0, stream>>>(XBA, Bp_a2, MSGA, SFA, NA);

    // ---- layer 2 aggregate+finish (no relu) -> f32 x2, in-place over Self ----
    agg_finish<false, false><<<NA / 4, 256, 0, stream>>>(MSGU, rp_a, eidx_ua,
                                                         SFA, b_ua2, SFA, NA);
    agg_finish<false, false><<<NU / 4, 256, 0, stream>>>(MSGA, rp_u, eidx_au,
                                                         SFU, b_au2, SFU, NU);

    // ---- head (el-CSR: xa row register-resident, gather users only) ----
    pred_csr<<<NA / 4, 256, 0, stream>>>(SFU, SFA, rp_el, elp, pred);
}

// Round 5
// 659.805 us; speedup vs baseline: 11.4568x; 1.1151x over previous
//
#include <hip/hip_runtime.h>

// Problem constants (match reference setup_inputs)
constexpr int NU  = 100000;   // users
constexpr int NA  = 20000;    // apps
constexpr int FU  = 32;
constexpr int FA  = 64;
constexpr int H   = 128;
constexpr int NE  = 1000000;  // edges per direction
constexpr int NEL = 500000;   // labeled pairs

constexpr int G_E  = (NE + 255) / 256;    // 3907 blocks per 1M-edge list
constexpr int G_EL = (NEL + 255) / 256;   // 1954
constexpr int NB_A = (NA + 1023) / 1024;  // 20
constexpr int NB_U = (NU + 1023) / 1024;  // 98
constexpr int NTOT = NA + NU + NA;        // deg/cur/incl layout: [a | u | el]

// filtered-fill geometry
constexpr int CH   = 1024;                 // edges per chunk
constexpr int CB_E = (NE + CH - 1) / CH;   // 977
constexpr int CB_L = (NEL + CH - 1) / CH;  // 489
constexpr int RA8  = (NA + 7) / 8;         // 2500 apps per XCD-range
constexpr int RU8  = (NU + 7) / 8;         // 12500 users per XCD-range

using bf16x8 = __attribute__((ext_vector_type(8))) short;
using f32x4  = __attribute__((ext_vector_type(4))) float;

__device__ inline unsigned short f2bf(float f) {
    union { float f; unsigned u; } x; x.f = f;
    unsigned u = x.u;
    return (unsigned short)((u + 0x7fffu + ((u >> 16) & 1u)) >> 16);  // RNE
}
__device__ inline float bf2f(unsigned short s) {
    union { unsigned u; float f; } x; x.u = ((unsigned)s) << 16;
    return x.f;
}

// ---------------------------------------------------------------------------
// Prologue: out[i,:] = bf16( emb[nid[i],:] + x[i,:] @ W + b )  (1 row / block)
// ---------------------------------------------------------------------------
template <int F>
__global__ __launch_bounds__(128)
void prologue_kernel(const float* __restrict__ x, const float* __restrict__ emb,
                     const float* __restrict__ W, const float* __restrict__ b,
                     const int* __restrict__ nid, unsigned short* __restrict__ out,
                     int N) {
    __shared__ float xs[F];
    int row = blockIdx.x;
    if (row >= N) return;
    int t = threadIdx.x;  // output column
    if (t < F) xs[t] = x[(size_t)row * F + t];
    __syncthreads();
    int id = nid[row];
    float acc = emb[(size_t)id * H + t] + b[t];
#pragma unroll
    for (int k = 0; k < F; ++k) acc += xs[k] * W[k * H + t];
    out[(size_t)row * H + t] = f2bf(acc);
}

// ---------------------------------------------------------------------------
// Merged CSR build over 3 graphs: u2a (dst=apps), a2u (dst=users), el (dst=apps)
// deg/cur layout bases: a=0, u=NA, el=NA+NU.  bsum bases: 0, 32, 160.
// rp bases: a=0 (NA+1), u=NA+1 (NU+1), el=NA+NU+2 (NA+1).
// ---------------------------------------------------------------------------
__global__ __launch_bounds__(256)
void hist_all(const int* __restrict__ d1, const int* __restrict__ d2,
              const int* __restrict__ d3, int* __restrict__ deg) {
    int b = blockIdx.x;
    if (b < G_E) {
        int e = b * 256 + threadIdx.x;
        if (e < NE) atomicAdd(&deg[d1[e]], 1);
    } else if (b < 2 * G_E) {
        int e = (b - G_E) * 256 + threadIdx.x;
        if (e < NE) atomicAdd(&deg[NA + d2[e]], 1);
    } else {
        int e = (b - 2 * G_E) * 256 + threadIdx.x;
        if (e < NEL) atomicAdd(&deg[NA + NU + d3[e]], 1);
    }
}

__global__ __launch_bounds__(1024)
void scan1_all(const int* __restrict__ deg, int* __restrict__ incl,
               int* __restrict__ bsum) {
    int b = blockIdx.x, t = threadIdx.x;
    int lb, n, base, bbase;
    if (b < NB_A)             { lb = b;              n = NA; base = 0;       bbase = 0;   }
    else if (b < NB_A + NB_U) { lb = b - NB_A;       n = NU; base = NA;      bbase = 32;  }
    else                      { lb = b - NB_A - NB_U; n = NA; base = NA + NU; bbase = 160; }
    __shared__ int s[1024];
    int i = lb * 1024 + t;
    s[t] = (i < n) ? deg[base + i] : 0;
    __syncthreads();
    for (int d = 1; d < 1024; d <<= 1) {
        int add = (t >= d) ? s[t - d] : 0;
        __syncthreads();
        s[t] += add;
        __syncthreads();
    }
    if (i < n) incl[base + i] = s[t];
    if (t == 1023) bsum[bbase + lb] = s[1023];
}

__global__ __launch_bounds__(1024)
void scan2_all(int* __restrict__ bsum) {
    int b = blockIdx.x, t = threadIdx.x;
    int nb, bbase;
    if (b == 0)      { nb = NB_A; bbase = 0;   }
    else if (b == 1) { nb = NB_U; bbase = 32;  }
    else             { nb = NB_A; bbase = 160; }
    __shared__ int s[1024];
    s[t] = (t < nb) ? bsum[bbase + t] : 0;
    __syncthreads();
    for (int d = 1; d < 1024; d <<= 1) {
        int add = (t >= d) ? s[t - d] : 0;
        __syncthreads();
        s[t] += add;
        __syncthreads();
    }
    if (t < nb) bsum[bbase + t] = s[t];
}

// writes rp and initializes the fill cursors (cur[i] = rp[i]) — no memset
__global__ __launch_bounds__(256)
void scan3_all(const int* __restrict__ incl, const int* __restrict__ bsum,
               int* __restrict__ rp, int* __restrict__ cur) {
    int i = blockIdx.x * 256 + threadIdx.x;
    if (i >= NTOT) return;
    int li, n, base, bbase, rbase;
    if (i < NA)           { li = i;           n = NA; base = 0;       bbase = 0;   rbase = 0;          }
    else if (i < NA + NU) { li = i - NA;      n = NU; base = NA;      bbase = 32;  rbase = NA + 1;     }
    else                  { li = i - NA - NU; n = NA; base = NA + NU; bbase = 160; rbase = NA + NU + 2; }
    int blk = li >> 10;
    int v = incl[base + li] + ((blk > 0) ? bsum[bbase + blk - 1] : 0);
    rp[rbase + li + 1] = v;
    if (li + 1 < n) cur[base + li + 1] = v;
    if (li == 0) { rp[rbase] = 0; cur[base] = 0; }
}

// ---------------------------------------------------------------------------
// XCD-range-filtered fill: block b -> range r = b&7, chunk g = b>>3.
// All eidx stores for dst range r are issued from (empirically) XCD r, so
// the scattered 4B writes accumulate in ONE L2 and write back full lines
// (round-4 fill_all: 162 MB write-through for 12 MB payload).
// ---------------------------------------------------------------------------
__global__ __launch_bounds__(256)
void fill_filtered(const int* __restrict__ s1, const int* __restrict__ d1,
                   const int* __restrict__ s2, const int* __restrict__ d2,
                   const int* __restrict__ s3, const int* __restrict__ d3,
                   int* __restrict__ cur, int* __restrict__ eidx_ua,
                   int* __restrict__ eidx_au, int2* __restrict__ elp) {
    int b = blockIdx.x;
    int r = b & 7;   // dst range (== XCD under round-robin dispatch)
    int g = b >> 3;  // chunk id across the 3 lists
    if (g < CB_E) {  // u2a: dst = apps
        int base = g * CH;
        for (int i = threadIdx.x; i < CH; i += 256) {
            int e = base + i;
            if (e >= NE) break;
            int d = d1[e];
            if (d / RA8 == r) {
                int pos = atomicAdd(&cur[d], 1);
                eidx_ua[pos] = s1[e];
            }
        }
    } else if (g < 2 * CB_E) {  // a2u: dst = users
        int base = (g - CB_E) * CH;
        for (int i = threadIdx.x; i < CH; i += 256) {
            int e = base + i;
            if (e >= NE) break;
            int d = d2[e];
            if (d / RU8 == r) {
                int pos = atomicAdd(&cur[NA + d], 1);
                eidx_au[pos] = s2[e];
            }
        }
    } else {  // el: dst = apps
        int base = (g - 2 * CB_E) * CH;
        for (int i = threadIdx.x; i < CH; i += 256) {
            int e = base + i;
            if (e >= NEL) break;
            int d = d3[e];
            if (d / RA8 == r) {
                int pos = atomicAdd(&cur[NA + NU + d], 1);
                elp[pos] = make_int2(s3[e], e);
            }
        }
    }
}

// ---------------------------------------------------------------------------
// Weight pack (all 4 GEMMs in one launch): Bp[which] fragment-ordered bf16.
// element ((n*4+ks)*64+l)*8+j holds W[k=ks*32+(l>>4)*8+j][n*16+(l&15)],
// W = [Wmsg | Wself] (128 x 256).
// ---------------------------------------------------------------------------
__global__ __launch_bounds__(256)
void pack_all(const float* __restrict__ Wm0, const float* __restrict__ Ws0,
              const float* __restrict__ Wm1, const float* __restrict__ Ws1,
              const float* __restrict__ Wm2, const float* __restrict__ Ws2,
              const float* __restrict__ Wm3, const float* __restrict__ Ws3,
              unsigned short* __restrict__ Bp) {
    int idx = blockIdx.x * 256 + threadIdx.x;  // 0 .. 4*32768-1
    int which = idx >> 15, li = idx & 32767;
    const float *Wm, *Ws;
    if (which == 0)      { Wm = Wm0; Ws = Ws0; }
    else if (which == 1) { Wm = Wm1; Ws = Ws1; }
    else if (which == 2) { Wm = Wm2; Ws = Ws2; }
    else                 { Wm = Wm3; Ws = Ws3; }
    int j = li & 7, l = (li >> 3) & 63, ks = (li >> 9) & 3, n = li >> 11;
    int ng = n * 16 + (l & 15);
    int kg = ks * 32 + (l >> 4) * 8 + j;
    float v = (n < 8) ? Wm[kg * H + ng] : Ws[kg * H + (ng - 128)];
    Bp[idx] = f2bf(v);
}

// ---------------------------------------------------------------------------
// Dense GEMM: [Msg | Self] = A @ [Wmsg | Wself], M x 128 x 256, bf16 MFMA.
// A is bf16 (direct fragment loads). Msg stored bf16, Self stored f32.
// Block = 256 thr (4 waves), BM=128 (wave: 2 m-tiles of 16 rows), full N=256.
// ---------------------------------------------------------------------------
__global__ __launch_bounds__(256)
void gemm_msg_self(const unsigned short* __restrict__ A,
                   const unsigned short* __restrict__ Bp,
                   unsigned short* __restrict__ Msg, float* __restrict__ Self,
                   int M) {
    __shared__ unsigned short Bs[32768];  // 64 KB packed weights
    int tid = threadIdx.x;
    {
        const int4* s = (const int4*)Bp;
        int4* d = (int4*)Bs;
#pragma unroll
        for (int i = 0; i < 16; ++i) d[tid + 256 * i] = s[tid + 256 * i];
    }
    __syncthreads();
    const int w = tid >> 6, l = tid & 63;
    const int l16 = l & 15, lg = l >> 4;
    const int r0 = blockIdx.x * 128 + w * 32;
    const int ra0 = min(r0 + l16, M - 1);       // A row, m-tile 0
    const int ra1 = min(r0 + 16 + l16, M - 1);  // A row, m-tile 1
    f32x4 acc0[16], acc1[16];
#pragma unroll
    for (int n = 0; n < 16; ++n) {
        acc0[n] = f32x4{0.f, 0.f, 0.f, 0.f};
        acc1[n] = f32x4{0.f, 0.f, 0.f, 0.f};
    }
#pragma unroll
    for (int ks = 0; ks < 4; ++ks) {
        bf16x8 a0 = *(const bf16x8*)(A + (size_t)ra0 * H + ks * 32 + lg * 8);
        bf16x8 a1 = *(const bf16x8*)(A + (size_t)ra1 * H + ks * 32 + lg * 8);
#pragma unroll
        for (int n = 0; n < 16; ++n) {
            bf16x8 bf = *(const bf16x8*)&Bs[((n * 4 + ks) * 64 + l) * 8];
            acc0[n] = __builtin_amdgcn_mfma_f32_16x16x32_bf16(a0, bf, acc0[n], 0, 0, 0);
            acc1[n] = __builtin_amdgcn_mfma_f32_16x16x32_bf16(a1, bf, acc1[n], 0, 0, 0);
        }
    }
    // C/D layout (m89-verified): col = lane&15, row = (lane>>4)*4 + j
#pragma unroll
    for (int n = 0; n < 16; ++n) {
#pragma unroll
        for (int j = 0; j < 4; ++j) {
            int rr0 = r0 + lg * 4 + j;
            int rr1 = rr0 + 16;
            if (n < 8) {
                int c = n * 16 + l16;
                if (rr0 < M) Msg[(size_t)rr0 * H + c] = f2bf(acc0[n][j]);
                if (rr1 < M) Msg[(size_t)rr1 * H + c] = f2bf(acc1[n][j]);
            } else {
                int c = (n - 8) * 16 + l16;
                if (rr0 < M) Self[(size_t)rr0 * H + c] = acc0[n][j];
                if (rr1 < M) Self[(size_t)rr1 * H + c] = acc1[n][j];
            }
        }
    }
}

// ---------------------------------------------------------------------------
// Aggregate + finish: tmp = mean_j Msg[eidx[j],:] + Self[i,:] + b
//   OUTBF16: out = bf16(relu(tmp))  (layer-1 features, GEMM-A format)
//   else:    out = tmp  f32, MAY ALIAS Self (per-thread read-before-write)
// One wave per dst row; lane handles cols {2l, 2l+1}; 4-deep gather ILP.
// ---------------------------------------------------------------------------
template <bool RELU, bool OUTBF16>
__global__ __launch_bounds__(256)
void agg_finish(const unsigned short* __restrict__ Msg,  // [Nsrc,H] bf16
                const int* __restrict__ rp, const int* __restrict__ eidx,
                const float* Self,                       // [N,H] f32 (no restrict: may alias out)
                const float* __restrict__ b,             // [H]
                void* outp, int N) {
    int w = threadIdx.x >> 6, l = threadIdx.x & 63;
    int row = blockIdx.x * 4 + w;
    if (row >= N) return;
    int beg = rp[row], end = rp[row + 1];
    float s = 1.0f / fmaxf((float)(end - beg), 1.0f);
    float a0 = 0.f, a1 = 0.f;
    int j = beg;
    for (; j + 3 < end; j += 4) {
        unsigned m0 = *(const unsigned*)(Msg + (size_t)eidx[j] * H + 2 * l);
        unsigned m1 = *(const unsigned*)(Msg + (size_t)eidx[j + 1] * H + 2 * l);
        unsigned m2 = *(const unsigned*)(Msg + (size_t)eidx[j + 2] * H + 2 * l);
        unsigned m3 = *(const unsigned*)(Msg + (size_t)eidx[j + 3] * H + 2 * l);
        a0 += bf2f((unsigned short)(m0 & 0xffff)) + bf2f((unsigned short)(m1 & 0xffff)) +
              bf2f((unsigned short)(m2 & 0xffff)) + bf2f((unsigned short)(m3 & 0xffff));
        a1 += bf2f((unsigned short)(m0 >> 16)) + bf2f((unsigned short)(m1 >> 16)) +
              bf2f((unsigned short)(m2 >> 16)) + bf2f((unsigned short)(m3 >> 16));
    }
    for (; j < end; ++j) {
        unsigned m0 = *(const unsigned*)(Msg + (size_t)eidx[j] * H + 2 * l);
        a0 += bf2f((unsigned short)(m0 & 0xffff));
        a1 += bf2f((unsigned short)(m0 >> 16));
    }
    float2 sf = *(const float2*)(Self + (size_t)row * H + 2 * l);
    float2 bb = *(const float2*)(b + 2 * l);
    float o0 = a0 * s + sf.x + bb.x;
    float o1 = a1 * s + sf.y + bb.y;
    if (RELU) { o0 = fmaxf(o0, 0.f); o1 = fmaxf(o1, 0.f); }
    if (OUTBF16) {
        unsigned pack = (unsigned)f2bf(o0) | ((unsigned)f2bf(o1) << 16);
        ((unsigned*)outp)[(size_t)row * (H / 2) + l] = pack;
    } else {
        ((float2*)outp)[(size_t)row * (H / 2) + l] = make_float2(o0, o1);
    }
}

// ---------------------------------------------------------------------------
// Head via el-CSR: one wave per app; xa row held in registers, only user rows
// gathered. pred[orig_e] = dot(xu2[u], xa2[app]).  2-deep edge ILP.
// ---------------------------------------------------------------------------
__global__ __launch_bounds__(256)
void pred_csr(const float* __restrict__ xu, const float* __restrict__ xa,
              const int* __restrict__ rp_el, const int2* __restrict__ elp,
              float* __restrict__ out) {
    int w = threadIdx.x >> 6, l = threadIdx.x & 63;
    int app = blockIdx.x * 4 + w;
    if (app >= NA) return;
    float2 a = *(const float2*)(xa + (size_t)app * H + 2 * l);
    int beg = rp_el[app], end = rp_el[app + 1];
    int j = beg;
    for (; j + 1 < end; j += 2) {
        int2 p0 = elp[j];
        int2 p1 = elp[j + 1];
        float2 u0 = *(const float2*)(xu + (size_t)p0.x * H + 2 * l);
        float2 u1 = *(const float2*)(xu + (size_t)p1.x * H + 2 * l);
        float v0 = u0.x * a.x + u0.y * a.y;
        float v1 = u1.x * a.x + u1.y * a.y;
#pragma unroll
        for (int off = 32; off > 0; off >>= 1) {
            v0 += __shfl_down(v0, off);
            v1 += __shfl_down(v1, off);
        }
        if (l == 0) { out[p0.y] = v0; out[p1.y] = v1; }
    }
    if (j < end) {
        int2 p0 = elp[j];
        float2 u0 = *(const float2*)(xu + (size_t)p0.x * H + 2 * l);
        float v0 = u0.x * a.x + u0.y * a.y;
#pragma unroll
        for (int off = 32; off > 0; off >>= 1) v0 += __shfl_down(v0, off);
        if (l == 0) out[p0.y] = v0;
    }
}

// ---------------------------------------------------------------------------
extern "C" void kernel_launch(void* const* d_in, const int* in_sizes, int n_in,
                              void* d_out, int out_size, void* d_ws, size_t ws_size,
                              hipStream_t stream) {
    const float* user_x     = (const float*)d_in[0];
    const float* app_x      = (const float*)d_in[1];
    const float* user_emb   = (const float*)d_in[2];
    const float* app_emb    = (const float*)d_in[3];
    const float* user_lin_W = (const float*)d_in[4];
    const float* user_lin_b = (const float*)d_in[5];
    const float* app_lin_W  = (const float*)d_in[6];
    const float* app_lin_b  = (const float*)d_in[7];
    const float* W_msg_ua1  = (const float*)d_in[8];
    const float* W_self_ua1 = (const float*)d_in[9];
    const float* b_ua1      = (const float*)d_in[10];
    const float* W_msg_au1  = (const float*)d_in[11];
    const float* W_self_au1 = (const float*)d_in[12];
    const float* b_au1      = (const float*)d_in[13];
    const float* W_msg_ua2  = (const float*)d_in[14];
    const float* W_self_ua2 = (const float*)d_in[15];
    const float* b_ua2      = (const float*)d_in[16];
    const float* W_msg_au2  = (const float*)d_in[17];
    const float* W_self_au2 = (const float*)d_in[18];
    const float* b_au2      = (const float*)d_in[19];
    const int*   user_n_id  = (const int*)d_in[20];
    const int*   app_n_id   = (const int*)d_in[21];
    const int*   e_src_u2a  = (const int*)d_in[22];
    const int*   e_dst_u2a  = (const int*)d_in[23];
    const int*   e_src_a2u  = (const int*)d_in[24];
    const int*   e_dst_a2u  = (const int*)d_in[25];
    const int*   el_src     = (const int*)d_in[26];
    const int*   el_dst     = (const int*)d_in[27];
    float* pred = (float*)d_out;
    (void)in_sizes; (void)n_in; (void)out_size; (void)ws_size;

    // ---- workspace layout (~137 MB; round-1 proved >=185 MB exists) ----
    char* p = (char*)d_ws;
    auto alloc = [&](size_t bytes) {
        char* r = p;
        p += (bytes + 255) & ~(size_t)255;
        return (void*)r;
    };
    float* SFU = (float*)alloc((size_t)NU * H * 4);   // Self_u (L1,L2) -> xu2 in-place
    float* SFA = (float*)alloc((size_t)NA * H * 4);   // Self_a (L1,L2) -> xa2 in-place
    unsigned short* XBU = (unsigned short*)alloc((size_t)NU * H * 2);  // x0_u then x1_u (bf16)
    unsigned short* XBA = (unsigned short*)alloc((size_t)NA * H * 2);  // x0_a then x1_a (bf16)
    unsigned short* MSGU = (unsigned short*)alloc((size_t)NU * H * 2); // bf16
    unsigned short* MSGA = (unsigned short*)alloc((size_t)NA * H * 2); // bf16
    int*  eidx_ua = (int*)alloc((size_t)NE * 4);      // u2a src users, dst-sorted by app
    int*  eidx_au = (int*)alloc((size_t)NE * 4);      // a2u src apps, dst-sorted by user
    int2* elp     = (int2*)alloc((size_t)NEL * 8);    // (user, orig_e), sorted by app
    int*  RP   = (int*)alloc((size_t)(NTOT + 3) * 4); // [rp_a | rp_u | rp_el]
    int*  deg  = (int*)alloc((size_t)NTOT * 4);       // [deg_a | deg_u | deg_el] -> cursors
    int*  incl = (int*)alloc((size_t)NTOT * 4);
    int*  bsum = (int*)alloc((size_t)256 * 4);
    unsigned short* Bp = (unsigned short*)alloc((size_t)4 * 32768 * 2);

    int* rp_a  = RP;
    int* rp_u  = RP + NA + 1;
    int* rp_el = RP + NA + NU + 2;
    unsigned short* Bp_u1 = Bp;
    unsigned short* Bp_a1 = Bp + 32768;
    unsigned short* Bp_u2 = Bp + 2 * 32768;
    unsigned short* Bp_a2 = Bp + 3 * 32768;

    const int gg_u = (NU + 127) / 128;
    const int gg_a = (NA + 127) / 128;

    // ---- prologue (writes bf16 features) ----
    prologue_kernel<FU><<<NU, 128, 0, stream>>>(user_x, user_emb, user_lin_W,
                                                user_lin_b, user_n_id, XBU, NU);
    prologue_kernel<FA><<<NA, 128, 0, stream>>>(app_x, app_emb, app_lin_W,
                                                app_lin_b, app_n_id, XBA, NA);

    // ---- weight packs (user pack: [W_msg_ua | W_self_au]; app: [W_msg_au | W_self_ua]) ----
    pack_all<<<512, 256, 0, stream>>>(W_msg_ua1, W_self_au1, W_msg_au1, W_self_ua1,
                                      W_msg_ua2, W_self_au2, W_msg_au2, W_self_ua2, Bp);

    // ---- merged CSR build (u2a, a2u, el) ----
    hipMemsetAsync(deg, 0, (size_t)NTOT * 4, stream);
    hist_all<<<2 * G_E + G_EL, 256, 0, stream>>>(e_dst_u2a, e_dst_a2u, el_dst, deg);
    scan1_all<<<NB_A + NB_U + NB_A, 1024, 0, stream>>>(deg, incl, bsum);
    scan2_all<<<3, 1024, 0, stream>>>(bsum);
    scan3_all<<<(NTOT + 255) / 256, 256, 0, stream>>>(incl, bsum, RP, deg);  // deg -> cursors
    fill_filtered<<<8 * (2 * CB_E + CB_L), 256, 0, stream>>>(
        e_src_u2a, e_dst_u2a, e_src_a2u, e_dst_a2u, el_src, el_dst, deg,
        eidx_ua, eidx_au, elp);

    // ---- layer 1 GEMMs: [Msg1 | Self1] = x0 @ [Wmsg | Wself] ----
    gemm_msg_self<<<gg_u, 256, 0, stream>>>(XBU, Bp_u1, MSGU, SFU, NU);
    gemm_msg_self<<<gg_a, 256, 0, stream>>>(XBA, Bp_a1, MSGA, SFA, NA);

    // ---- layer 1 aggregate+finish -> bf16 x1 (overwrites dead x0) ----
    agg_finish<true, true><<<NA / 4, 256, 0, stream>>>(MSGU, rp_a, eidx_ua,
                                                       SFA, b_ua1, XBA, NA);
    agg_finish<true, true><<<NU / 4, 256, 0, stream>>>(MSGA, rp_u, eidx_au,
                                                       SFU, b_au1, XBU, NU);

    // ---- layer 2 GEMMs: [Msg2 | Self2] = x1 @ [Wmsg | Wself] ----
    gemm_msg_self<<<gg_u, 256, 0, stream>>>(XBU, Bp_u2, MSGU, SFU, NU);
    gemm_msg_self<<<gg_a, 256, 0, stream>>>(XBA, Bp_a2, MSGA, SFA, NA);

    // ---- layer 2 aggregate+finish (no relu) -> f32 x2, in-place over Self ----
    agg_finish<false, false><<<NA / 4, 256, 0, stream>>>(MSGU, rp_a, eidx_ua,
                                                         SFA, b_ua2, SFA, NA);
    agg_finish<false, false><<<NU / 4, 256, 0, stream>>>(MSGA, rp_u, eidx_au,
                                                         SFU, b_au2, SFU, NU);

    // ---- head (el-CSR: xa row register-resident, gather users only) ----
    pred_csr<<<NA / 4, 256, 0, stream>>>(SFU, SFA, rp_el, elp, pred);
}

// Round 6
// 481.025 us; speedup vs baseline: 15.7149x; 1.3717x over previous
//
#include <hip/hip_runtime.h>

// Problem constants (match reference setup_inputs)
constexpr int NU  = 100000;   // users
constexpr int NA  = 20000;    // apps
constexpr int FU  = 32;
constexpr int FA  = 64;
constexpr int H   = 128;
constexpr int NE  = 1000000;  // edges per direction
constexpr int NEL = 500000;   // labeled pairs

// bucket-sort geometry
constexpr int NBK  = 256;                 // coarse buckets per graph
constexpr int ECH  = 8192;                // edges per hist/phaseA block
constexpr int BK_E = (NE + ECH - 1) / ECH;   // 123
constexpr int BK_L = (NEL + ECH - 1) / ECH;  // 62
constexpr int HB   = 2 * BK_E + BK_L;        // 308 hist blocks
constexpr int PB_U = NU / 2;              // 50000 prologue blocks (2 rows each)
constexpr int PB_A = NA / 2;              // 10000
constexpr int PACKB = 512;                // 4*32768 / 256
constexpr int GG_U = (NU + 127) / 128;    // 782
constexpr int GG_A = (NA + 127) / 128;    // 157
constexpr int GA_A = NA / 4;              // 5000
constexpr int GA_U = NU / 4;              // 25000

using bf16x8 = __attribute__((ext_vector_type(8))) short;
using f32x4  = __attribute__((ext_vector_type(4))) float;

__device__ inline unsigned short f2bf(float f) {
    union { float f; unsigned u; } x; x.f = f;
    unsigned u = x.u;
    return (unsigned short)((u + 0x7fffu + ((u >> 16) & 1u)) >> 16);  // RNE
}
__device__ inline float bf2f(unsigned short s) {
    union { unsigned u; float f; } x; x.u = ((unsigned)s) << 16;
    return x.f;
}
__device__ inline int buckA(int d) { return (int)(((unsigned)d * 256u) / 20000u); }
__device__ inline int buckU(int d) { return (int)(((unsigned)d * 256u) / 100000u); }

// ---------------------------------------------------------------------------
// K1 mega-kernel: [hist_coarse | prologue_user | prologue_app | pack]
// All independent work, merged for overlap + fewer dispatches.
// ---------------------------------------------------------------------------
__global__ __launch_bounds__(256)
void k1_kernel(const int* __restrict__ d1, const int* __restrict__ d2,
               const int* __restrict__ d3, int* __restrict__ gcnt,
               const float* __restrict__ user_x, const float* __restrict__ user_emb,
               const float* __restrict__ user_lin_W, const float* __restrict__ user_lin_b,
               const int* __restrict__ user_n_id, unsigned short* __restrict__ XBU,
               const float* __restrict__ app_x, const float* __restrict__ app_emb,
               const float* __restrict__ app_lin_W, const float* __restrict__ app_lin_b,
               const int* __restrict__ app_n_id, unsigned short* __restrict__ XBA,
               const float* __restrict__ Wm0, const float* __restrict__ Ws0,
               const float* __restrict__ Wm1, const float* __restrict__ Ws1,
               const float* __restrict__ Wm2, const float* __restrict__ Ws2,
               const float* __restrict__ Wm3, const float* __restrict__ Ws3,
               unsigned short* __restrict__ Bp) {
    __shared__ int hs[256];
    __shared__ float xs[2][64];
    int bid = blockIdx.x, tid = threadIdx.x;
    if (bid < HB) {
        // ---- coarse 256-bucket histogram over the 3 dst lists ----
        int g, base, n;
        const int* dl;
        if (bid < BK_E)          { g = 0; base = bid * ECH;            dl = d1; n = NE;  }
        else if (bid < 2 * BK_E) { g = 1; base = (bid - BK_E) * ECH;   dl = d2; n = NE;  }
        else                     { g = 2; base = (bid - 2 * BK_E) * ECH; dl = d3; n = NEL; }
        hs[tid] = 0;
        __syncthreads();
        for (int i = tid; i < ECH; i += 256) {
            int e = base + i;
            if (e >= n) break;
            int d = __builtin_nontemporal_load(&dl[e]);
            int b = (g == 1) ? buckU(d) : buckA(d);
            atomicAdd(&hs[b], 1);
        }
        __syncthreads();
        if (hs[tid] > 0) atomicAdd(&gcnt[g * 256 + tid], hs[tid]);
    } else if (bid < HB + PB_U) {
        // ---- user prologue, 2 rows per block ----
        int blk = bid - HB, w = tid >> 7, t = tid & 127;
        int row = blk * 2 + w;
        if (t < FU) xs[w][t] = user_x[(size_t)row * FU + t];
        __syncthreads();
        float acc = user_emb[(size_t)user_n_id[row] * H + t] + user_lin_b[t];
#pragma unroll
        for (int k = 0; k < FU; ++k) acc += xs[w][k] * user_lin_W[k * H + t];
        XBU[(size_t)row * H + t] = f2bf(acc);
    } else if (bid < HB + PB_U + PB_A) {
        // ---- app prologue, 2 rows per block ----
        int blk = bid - HB - PB_U, w = tid >> 7, t = tid & 127;
        int row = blk * 2 + w;
        if (t < FA) xs[w][t] = app_x[(size_t)row * FA + t];
        __syncthreads();
        float acc = app_emb[(size_t)app_n_id[row] * H + t] + app_lin_b[t];
#pragma unroll
        for (int k = 0; k < FA; ++k) acc += xs[w][k] * app_lin_W[k * H + t];
        XBA[(size_t)row * H + t] = f2bf(acc);
    } else {
        // ---- weight pack: Bp fragment-ordered bf16, [Wmsg | Wself] 128x256 ----
        int idx = (bid - HB - PB_U - PB_A) * 256 + tid;  // 0 .. 131071
        int which = idx >> 15, li = idx & 32767;
        const float *Wm, *Ws;
        if (which == 0)      { Wm = Wm0; Ws = Ws0; }
        else if (which == 1) { Wm = Wm1; Ws = Ws1; }
        else if (which == 2) { Wm = Wm2; Ws = Ws2; }
        else                 { Wm = Wm3; Ws = Ws3; }
        int j = li & 7, l = (li >> 3) & 63, ks = (li >> 9) & 3, n = li >> 11;
        int ng = n * 16 + (l & 15);
        int kg = ks * 32 + (l >> 4) * 8 + j;
        float v = (n < 8) ? Wm[kg * H + ng] : Ws[kg * H + (ng - 128)];
        Bp[idx] = f2bf(v);
    }
}

// ---------------------------------------------------------------------------
// scan_coarse: 1 block; per graph: inclusive scan of 256 bucket counts ->
// cb (bucket row_ptr) and gcur (phaseA cursors = exclusive scan).
// ---------------------------------------------------------------------------
__global__ __launch_bounds__(256)
void scanc_kernel(const int* __restrict__ gcnt, int* __restrict__ cb,
                  int* __restrict__ gcur) {
    __shared__ int s[256];
    int t = threadIdx.x;
    for (int g = 0; g < 3; ++g) {
        int v = gcnt[g * 256 + t];
        s[t] = v;
        __syncthreads();
        for (int d = 1; d < 256; d <<= 1) {
            int a = (t >= d) ? s[t - d] : 0;
            __syncthreads();
            s[t] += a;
            __syncthreads();
        }
        cb[g * 257 + t + 1] = s[t];
        if (t == 0) cb[g * 257] = 0;
        gcur[g * 256 + t] = s[t] - v;
        __syncthreads();
    }
}

// ---------------------------------------------------------------------------
// phaseA: bin (payload,dst) pairs into exact bucket regions.
// Per block: LDS bucket counts -> one global atomicAdd per nonempty bucket
// (contiguous reservation, ~32 pairs = 256 B runs -> full-line writebacks).
// ---------------------------------------------------------------------------
__global__ __launch_bounds__(256)
void phaseA_kernel(const int* __restrict__ s1, const int* __restrict__ d1,
                   const int* __restrict__ s2, const int* __restrict__ d2,
                   const int* __restrict__ d3, int* __restrict__ gcur,
                   int2* __restrict__ bp0, int2* __restrict__ bp1,
                   int2* __restrict__ bp2) {
    __shared__ int cnt[256], gb[256], cur[256];
    int bid = blockIdx.x, tid = threadIdx.x;
    int g, base, n;
    const int *dl, *sl;
    int2* bp;
    if (bid < BK_E)          { g = 0; base = bid * ECH;              dl = d1; sl = s1; n = NE;  bp = bp0; }
    else if (bid < 2 * BK_E) { g = 1; base = (bid - BK_E) * ECH;     dl = d2; sl = s2; n = NE;  bp = bp1; }
    else                     { g = 2; base = (bid - 2 * BK_E) * ECH; dl = d3; sl = nullptr; n = NEL; bp = bp2; }
    cnt[tid] = 0;
    cur[tid] = 0;
    __syncthreads();
    for (int i = tid; i < ECH; i += 256) {
        int e = base + i;
        if (e >= n) break;
        int d = __builtin_nontemporal_load(&dl[e]);
        int b = (g == 1) ? buckU(d) : buckA(d);
        atomicAdd(&cnt[b], 1);
    }
    __syncthreads();
    if (cnt[tid] > 0) gb[tid] = atomicAdd(&gcur[g * 256 + tid], cnt[tid]);
    __syncthreads();
    for (int i = tid; i < ECH; i += 256) {
        int e = base + i;
        if (e >= n) break;
        int d = __builtin_nontemporal_load(&dl[e]);
        int b = (g == 1) ? buckU(d) : buckA(d);
        int payload = (g == 2) ? e : __builtin_nontemporal_load(&sl[e]);
        int pos = gb[b] + atomicAdd(&cur[b], 1);
        bp[pos] = make_int2(payload, d);
    }
}

// ---------------------------------------------------------------------------
// phaseB: one block per (graph,bucket). Local per-dst hist + scan in LDS,
// write rp directly, scatter payloads into a contiguous ~16 KB region.
// ---------------------------------------------------------------------------
__global__ __launch_bounds__(256)
void phaseB_kernel(const int2* __restrict__ bp0, const int2* __restrict__ bp1,
                   const int2* __restrict__ bp2, const int* __restrict__ cb,
                   const int* __restrict__ el_src, int* __restrict__ eidx_ua,
                   int* __restrict__ eidx_au, int2* __restrict__ elp,
                   int* __restrict__ rp_a, int* __restrict__ rp_u,
                   int* __restrict__ rp_el) {
    __shared__ int cnt[400], rpl[400];
    int bid = blockIdx.x, tid = threadIdx.x;
    int g = bid >> 8, b = bid & 255;
    const int2* bp;
    int Nd;
    int* rp;
    if (g == 0)      { bp = bp0; Nd = NA; rp = rp_a;  }
    else if (g == 1) { bp = bp1; Nd = NU; rp = rp_u;  }
    else             { bp = bp2; Nd = NA; rp = rp_el; }
    int lo = (b * Nd + 255) >> 8, hi = ((b + 1) * Nd + 255) >> 8;
    int nd = hi - lo;
    int ebase = cb[g * 257 + b];
    int ecnt  = cb[g * 257 + b + 1] - ebase;
    for (int i = tid; i < nd; i += 256) cnt[i] = 0;
    __syncthreads();
    for (int i = tid; i < ecnt; i += 256) {
        long long v = __builtin_nontemporal_load((const long long*)&bp[ebase + i]);
        int d = (int)(v >> 32);
        atomicAdd(&cnt[d - lo], 1);
    }
    __syncthreads();
    if (tid == 0) {  // serial exclusive scan (nd <= 391)
        int run = 0;
        for (int i = 0; i < nd; ++i) { rpl[i] = run; run += cnt[i]; }
    }
    __syncthreads();
    for (int i = tid; i < nd; i += 256) {
        rp[lo + i] = ebase + rpl[i];
        cnt[i] = rpl[i];  // convert to cursor
    }
    if (b == 255 && tid == 0) rp[Nd] = ebase + ecnt;
    __syncthreads();
    for (int i = tid; i < ecnt; i += 256) {
        long long v = __builtin_nontemporal_load((const long long*)&bp[ebase + i]);
        int payload = (int)v, d = (int)(v >> 32);
        int pos = ebase + atomicAdd(&cnt[d - lo], 1);
        if (g == 0)      eidx_ua[pos] = payload;
        else if (g == 1) eidx_au[pos] = payload;
        else             elp[pos] = make_int2(el_src[payload], payload);
    }
}

// ---------------------------------------------------------------------------
// Merged dense GEMM (user + app halves): [Msg | Self] = A @ [Wmsg | Wself],
// M x 128 x 256, bf16 MFMA. Msg stored bf16, Self stored f32.
// ---------------------------------------------------------------------------
__global__ __launch_bounds__(256)
void gemm2_kernel(const unsigned short* __restrict__ Au,
                  const unsigned short* __restrict__ Aa,
                  const unsigned short* __restrict__ BpU,
                  const unsigned short* __restrict__ BpA,
                  unsigned short* __restrict__ MsgU, unsigned short* __restrict__ MsgA,
                  float* __restrict__ SelfU, float* __restrict__ SelfA) {
    __shared__ unsigned short Bs[32768];  // 64 KB packed weights
    int bid = blockIdx.x, tid = threadIdx.x;
    const unsigned short *A, *Bp;
    unsigned short* Msg;
    float* Self;
    int M, blk;
    if (bid < GG_U) { A = Au; Bp = BpU; Msg = MsgU; Self = SelfU; M = NU; blk = bid; }
    else            { A = Aa; Bp = BpA; Msg = MsgA; Self = SelfA; M = NA; blk = bid - GG_U; }
    {
        const int4* s = (const int4*)Bp;
        int4* d = (int4*)Bs;
#pragma unroll
        for (int i = 0; i < 16; ++i) d[tid + 256 * i] = s[tid + 256 * i];
    }
    __syncthreads();
    const int w = tid >> 6, l = tid & 63;
    const int l16 = l & 15, lg = l >> 4;
    const int r0 = blk * 128 + w * 32;
    const int ra0 = min(r0 + l16, M - 1);
    const int ra1 = min(r0 + 16 + l16, M - 1);
    f32x4 acc0[16], acc1[16];
#pragma unroll
    for (int n = 0; n < 16; ++n) {
        acc0[n] = f32x4{0.f, 0.f, 0.f, 0.f};
        acc1[n] = f32x4{0.f, 0.f, 0.f, 0.f};
    }
#pragma unroll
    for (int ks = 0; ks < 4; ++ks) {
        bf16x8 a0 = *(const bf16x8*)(A + (size_t)ra0 * H + ks * 32 + lg * 8);
        bf16x8 a1 = *(const bf16x8*)(A + (size_t)ra1 * H + ks * 32 + lg * 8);
#pragma unroll
        for (int n = 0; n < 16; ++n) {
            bf16x8 bf = *(const bf16x8*)&Bs[((n * 4 + ks) * 64 + l) * 8];
            acc0[n] = __builtin_amdgcn_mfma_f32_16x16x32_bf16(a0, bf, acc0[n], 0, 0, 0);
            acc1[n] = __builtin_amdgcn_mfma_f32_16x16x32_bf16(a1, bf, acc1[n], 0, 0, 0);
        }
    }
    // C/D layout (m89-verified): col = lane&15, row = (lane>>4)*4 + j
#pragma unroll
    for (int n = 0; n < 16; ++n) {
#pragma unroll
        for (int j = 0; j < 4; ++j) {
            int rr0 = r0 + lg * 4 + j;
            int rr1 = rr0 + 16;
            if (n < 8) {
                int c = n * 16 + l16;
                if (rr0 < M) Msg[(size_t)rr0 * H + c] = f2bf(acc0[n][j]);
                if (rr1 < M) Msg[(size_t)rr1 * H + c] = f2bf(acc1[n][j]);
            } else {
                int c = (n - 8) * 16 + l16;
                if (rr0 < M) Self[(size_t)rr0 * H + c] = acc0[n][j];
                if (rr1 < M) Self[(size_t)rr1 * H + c] = acc1[n][j];
            }
        }
    }
}

// ---------------------------------------------------------------------------
// Merged aggregate+finish (app half then user half):
//   tmp = mean_j Msg[eidx[j],:] + Self[i,:] + b
//   OUTBF16: out = bf16(relu(tmp));  else: out = tmp f32 (may alias Self)
// One wave per dst row; lane handles cols {2l, 2l+1}; 4-deep gather ILP.
// ---------------------------------------------------------------------------
template <bool RELU, bool OUTBF16>
__global__ __launch_bounds__(256)
void agg2_kernel(const unsigned short* __restrict__ MsgU,
                 const unsigned short* __restrict__ MsgA,
                 const int* __restrict__ rp_a, const int* __restrict__ rp_u,
                 const int* __restrict__ eidx_ua, const int* __restrict__ eidx_au,
                 const float* SelfA, const float* SelfU,
                 const float* __restrict__ bA, const float* __restrict__ bU,
                 void* outA, void* outU) {
    int bid = blockIdx.x;
    int w = threadIdx.x >> 6, l = threadIdx.x & 63;
    const unsigned short* Msg;
    const int *rp, *eidx;
    const float *Self, *bb_;
    void* outp;
    int row;
    if (bid < GA_A) { Msg = MsgU; rp = rp_a; eidx = eidx_ua; Self = SelfA; bb_ = bA; outp = outA; row = bid * 4 + w; }
    else            { Msg = MsgA; rp = rp_u; eidx = eidx_au; Self = SelfU; bb_ = bU; outp = outU; row = (bid - GA_A) * 4 + w; }
    int beg = rp[row], end = rp[row + 1];
    float s = 1.0f / fmaxf((float)(end - beg), 1.0f);
    float a0 = 0.f, a1 = 0.f;
    int j = beg;
    for (; j + 3 < end; j += 4) {
        unsigned m0 = *(const unsigned*)(Msg + (size_t)eidx[j] * H + 2 * l);
        unsigned m1 = *(const unsigned*)(Msg + (size_t)eidx[j + 1] * H + 2 * l);
        unsigned m2 = *(const unsigned*)(Msg + (size_t)eidx[j + 2] * H + 2 * l);
        unsigned m3 = *(const unsigned*)(Msg + (size_t)eidx[j + 3] * H + 2 * l);
        a0 += bf2f((unsigned short)(m0 & 0xffff)) + bf2f((unsigned short)(m1 & 0xffff)) +
              bf2f((unsigned short)(m2 & 0xffff)) + bf2f((unsigned short)(m3 & 0xffff));
        a1 += bf2f((unsigned short)(m0 >> 16)) + bf2f((unsigned short)(m1 >> 16)) +
              bf2f((unsigned short)(m2 >> 16)) + bf2f((unsigned short)(m3 >> 16));
    }
    for (; j < end; ++j) {
        unsigned m0 = *(const unsigned*)(Msg + (size_t)eidx[j] * H + 2 * l);
        a0 += bf2f((unsigned short)(m0 & 0xffff));
        a1 += bf2f((unsigned short)(m0 >> 16));
    }
    float2 sf = *(const float2*)(Self + (size_t)row * H + 2 * l);
    float2 bv = *(const float2*)(bb_ + 2 * l);
    float o0 = a0 * s + sf.x + bv.x;
    float o1 = a1 * s + sf.y + bv.y;
    if (RELU) { o0 = fmaxf(o0, 0.f); o1 = fmaxf(o1, 0.f); }
    if (OUTBF16) {
        unsigned pack = (unsigned)f2bf(o0) | ((unsigned)f2bf(o1) << 16);
        ((unsigned*)outp)[(size_t)row * (H / 2) + l] = pack;
    } else {
        ((float2*)outp)[(size_t)row * (H / 2) + l] = make_float2(o0, o1);
    }
}

// ---------------------------------------------------------------------------
// Head via el-CSR: one wave per app; xa row in registers, gather user rows.
// ---------------------------------------------------------------------------
__global__ __launch_bounds__(256)
void pred_csr(const float* __restrict__ xu, const float* __restrict__ xa,
              const int* __restrict__ rp_el, const int2* __restrict__ elp,
              float* __restrict__ out) {
    int w = threadIdx.x >> 6, l = threadIdx.x & 63;
    int app = blockIdx.x * 4 + w;
    if (app >= NA) return;
    float2 a = *(const float2*)(xa + (size_t)app * H + 2 * l);
    int beg = rp_el[app], end = rp_el[app + 1];
    int j = beg;
    for (; j + 1 < end; j += 2) {
        int2 p0 = elp[j];
        int2 p1 = elp[j + 1];
        float2 u0 = *(const float2*)(xu + (size_t)p0.x * H + 2 * l);
        float2 u1 = *(const float2*)(xu + (size_t)p1.x * H + 2 * l);
        float v0 = u0.x * a.x + u0.y * a.y;
        float v1 = u1.x * a.x + u1.y * a.y;
#pragma unroll
        for (int off = 32; off > 0; off >>= 1) {
            v0 += __shfl_down(v0, off);
            v1 += __shfl_down(v1, off);
        }
        if (l == 0) { out[p0.y] = v0; out[p1.y] = v1; }
    }
    if (j < end) {
        int2 p0 = elp[j];
        float2 u0 = *(const float2*)(xu + (size_t)p0.x * H + 2 * l);
        float v0 = u0.x * a.x + u0.y * a.y;
#pragma unroll
        for (int off = 32; off > 0; off >>= 1) v0 += __shfl_down(v0, off);
        if (l == 0) out[p0.y] = v0;
    }
}

// ---------------------------------------------------------------------------
extern "C" void kernel_launch(void* const* d_in, const int* in_sizes, int n_in,
                              void* d_out, int out_size, void* d_ws, size_t ws_size,
                              hipStream_t stream) {
    const float* user_x     = (const float*)d_in[0];
    const float* app_x      = (const float*)d_in[1];
    const float* user_emb   = (const float*)d_in[2];
    const float* app_emb    = (const float*)d_in[3];
    const float* user_lin_W = (const float*)d_in[4];
    const float* user_lin_b = (const float*)d_in[5];
    const float* app_lin_W  = (const float*)d_in[6];
    const float* app_lin_b  = (const float*)d_in[7];
    const float* W_msg_ua1  = (const float*)d_in[8];
    const float* W_self_ua1 = (const float*)d_in[9];
    const float* b_ua1      = (const float*)d_in[10];
    const float* W_msg_au1  = (const float*)d_in[11];
    const float* W_self_au1 = (const float*)d_in[12];
    const float* b_au1      = (const float*)d_in[13];
    const float* W_msg_ua2  = (const float*)d_in[14];
    const float* W_self_ua2 = (const float*)d_in[15];
    const float* b_ua2      = (const float*)d_in[16];
    const float* W_msg_au2  = (const float*)d_in[17];
    const float* W_self_au2 = (const float*)d_in[18];
    const float* b_au2      = (const float*)d_in[19];
    const int*   user_n_id  = (const int*)d_in[20];
    const int*   app_n_id   = (const int*)d_in[21];
    const int*   e_src_u2a  = (const int*)d_in[22];
    const int*   e_dst_u2a  = (const int*)d_in[23];
    const int*   e_src_a2u  = (const int*)d_in[24];
    const int*   e_dst_a2u  = (const int*)d_in[25];
    const int*   el_src     = (const int*)d_in[26];
    const int*   el_dst     = (const int*)d_in[27];
    float* pred = (float*)d_out;
    (void)in_sizes; (void)n_in; (void)out_size; (void)ws_size;

    // ---- workspace layout (~156 MB; round-1 proved >=185 MB exists) ----
    char* p = (char*)d_ws;
    auto alloc = [&](size_t bytes) {
        char* r = p;
        p += (bytes + 255) & ~(size_t)255;
        return (void*)r;
    };
    float* SFU = (float*)alloc((size_t)NU * H * 4);   // Self_u -> xu2 in-place
    float* SFA = (float*)alloc((size_t)NA * H * 4);   // Self_a -> xa2 in-place
    unsigned short* XBU = (unsigned short*)alloc((size_t)NU * H * 2);  // x0_u then x1_u
    unsigned short* XBA = (unsigned short*)alloc((size_t)NA * H * 2);  // x0_a then x1_a
    unsigned short* MSGU = (unsigned short*)alloc((size_t)NU * H * 2);
    unsigned short* MSGA = (unsigned short*)alloc((size_t)NA * H * 2);
    int*  eidx_ua = (int*)alloc((size_t)NE * 4);
    int*  eidx_au = (int*)alloc((size_t)NE * 4);
    int2* elp     = (int2*)alloc((size_t)NEL * 8);    // (user, orig_e), app-sorted
    int2* bp0     = (int2*)alloc((size_t)NE * 8);     // phaseA bins (payload,dst)
    int2* bp1     = (int2*)alloc((size_t)NE * 8);
    int2* bp2     = (int2*)alloc((size_t)NEL * 8);
    int*  RP   = (int*)alloc((size_t)(NA + NU + NA + 3) * 4);  // [rp_a|rp_u|rp_el]
    int*  gcnt = (int*)alloc((size_t)768 * 4);
    int*  gcur = (int*)alloc((size_t)768 * 4);
    int*  cb   = (int*)alloc((size_t)(3 * 257) * 4);
    unsigned short* Bp = (unsigned short*)alloc((size_t)4 * 32768 * 2);

    int* rp_a  = RP;
    int* rp_u  = RP + NA + 1;
    int* rp_el = RP + NA + NU + 2;
    unsigned short* Bp_u1 = Bp;
    unsigned short* Bp_a1 = Bp + 32768;
    unsigned short* Bp_u2 = Bp + 2 * 32768;
    unsigned short* Bp_a2 = Bp + 3 * 32768;

    // ---- K1: hist_coarse + prologues + weight pack (independent, merged) ----
    hipMemsetAsync(gcnt, 0, 768 * 4, stream);
    k1_kernel<<<HB + PB_U + PB_A + PACKB, 256, 0, stream>>>(
        e_dst_u2a, e_dst_a2u, el_dst, gcnt,
        user_x, user_emb, user_lin_W, user_lin_b, user_n_id, XBU,
        app_x, app_emb, app_lin_W, app_lin_b, app_n_id, XBA,
        W_msg_ua1, W_self_au1, W_msg_au1, W_self_ua1,
        W_msg_ua2, W_self_au2, W_msg_au2, W_self_ua2, Bp);

    // ---- bucket-sort CSR build ----
    scanc_kernel<<<1, 256, 0, stream>>>(gcnt, cb, gcur);
    phaseA_kernel<<<HB, 256, 0, stream>>>(e_src_u2a, e_dst_u2a, e_src_a2u,
                                          e_dst_a2u, el_dst, gcur, bp0, bp1, bp2);
    phaseB_kernel<<<768, 256, 0, stream>>>(bp0, bp1, bp2, cb, el_src,
                                           eidx_ua, eidx_au, elp,
                                           rp_a, rp_u, rp_el);

    // ---- layer 1: GEMMs then aggregate+finish -> bf16 x1 ----
    gemm2_kernel<<<GG_U + GG_A, 256, 0, stream>>>(XBU, XBA, Bp_u1, Bp_a1,
                                                  MSGU, MSGA, SFU, SFA);
    agg2_kernel<true, true><<<GA_A + GA_U, 256, 0, stream>>>(
        MSGU, MSGA, rp_a, rp_u, eidx_ua, eidx_au, SFA, SFU, b_ua1, b_au1,
        XBA, XBU);

    // ---- layer 2: GEMMs then aggregate+finish -> f32 x2 in-place over Self ----
    gemm2_kernel<<<GG_U + GG_A, 256, 0, stream>>>(XBU, XBA, Bp_u2, Bp_a2,
                                                  MSGU, MSGA, SFU, SFA);
    agg2_kernel<false, false><<<GA_A + GA_U, 256, 0, stream>>>(
        MSGU, MSGA, rp_a, rp_u, eidx_ua, eidx_au, SFA, SFU, b_ua2, b_au2,
        SFA, SFU);

    // ---- head ----
    pred_csr<<<NA / 4, 256, 0, stream>>>(SFU, SFA, rp_el, elp, pred);
}

// Round 7
// 440.080 us; speedup vs baseline: 17.1771x; 1.0930x over previous
//
#include <hip/hip_runtime.h>

// Problem constants (match reference setup_inputs)
constexpr int NU  = 100000;   // users
constexpr int NA  = 20000;    // apps
constexpr int FU  = 32;
constexpr int FA  = 64;
constexpr int H   = 128;
constexpr int NE  = 1000000;  // edges per direction
constexpr int NEL = 500000;   // labeled pairs

// bucket-sort geometry
constexpr int ECH  = 8192;                // edges per hist/phaseA block
constexpr int BK_E = (NE + ECH - 1) / ECH;   // 123
constexpr int BK_L = (NEL + ECH - 1) / ECH;  // 62
constexpr int HB   = 2 * BK_E + BK_L;        // 308 hist blocks
constexpr int PB_U = NU / 8;              // 12500 prologue blocks (8 rows each)
constexpr int PB_A = NA / 8;              // 2500
constexpr int PACKB = 512;                // 4*32768 / 256
constexpr int GG_U = (NU + 127) / 128;    // 782
constexpr int GG_A = (NA + 127) / 128;    // 157
constexpr int GA_A = NA / 4;              // 5000
constexpr int GA_U = NU / 4;              // 25000

using bf16x8 = __attribute__((ext_vector_type(8))) short;
using f32x4  = __attribute__((ext_vector_type(4))) float;

__device__ inline unsigned short f2bf(float f) {
    union { float f; unsigned u; } x; x.f = f;
    unsigned u = x.u;
    return (unsigned short)((u + 0x7fffu + ((u >> 16) & 1u)) >> 16);  // RNE
}
__device__ inline float bf2f(unsigned short s) {
    union { unsigned u; float f; } x; x.u = ((unsigned)s) << 16;
    return x.f;
}
__device__ inline int buckA(int d) { return (int)(((unsigned)d * 256u) / 20000u); }
__device__ inline int buckU(int d) { return (int)(((unsigned)d * 256u) / 100000u); }

// ---------------------------------------------------------------------------
// K1 mega-kernel: [hist_coarse | prologue_user | prologue_app | pack]
// Prologue: 8 rows/block, thread=(row, 4-col group), float4 loads, uint2 store.
// Hist: per-wave private LDS sub-histograms (cuts atomic contention).
// ---------------------------------------------------------------------------
__global__ __launch_bounds__(256)
void k1_kernel(const int* __restrict__ d1, const int* __restrict__ d2,
               const int* __restrict__ d3, int* __restrict__ gcnt,
               const float* __restrict__ user_x, const float* __restrict__ user_emb,
               const float* __restrict__ user_lin_W, const float* __restrict__ user_lin_b,
               const int* __restrict__ user_n_id, unsigned short* __restrict__ XBU,
               const float* __restrict__ app_x, const float* __restrict__ app_emb,
               const float* __restrict__ app_lin_W, const float* __restrict__ app_lin_b,
               const int* __restrict__ app_n_id, unsigned short* __restrict__ XBA,
               const float* __restrict__ Wm0, const float* __restrict__ Ws0,
               const float* __restrict__ Wm1, const float* __restrict__ Ws1,
               const float* __restrict__ Wm2, const float* __restrict__ Ws2,
               const float* __restrict__ Wm3, const float* __restrict__ Ws3,
               unsigned short* __restrict__ Bp) {
    __shared__ int hs4[4][256];
    __shared__ float xs[8][64];
    int bid = blockIdx.x, tid = threadIdx.x;
    if (bid < HB) {
        // ---- coarse 256-bucket histogram over the 3 dst lists ----
        int g, base, n;
        const int* dl;
        if (bid < BK_E)          { g = 0; base = bid * ECH;              dl = d1; n = NE;  }
        else if (bid < 2 * BK_E) { g = 1; base = (bid - BK_E) * ECH;     dl = d2; n = NE;  }
        else                     { g = 2; base = (bid - 2 * BK_E) * ECH; dl = d3; n = NEL; }
        for (int i = tid; i < 1024; i += 256) ((int*)hs4)[i] = 0;
        __syncthreads();
        int wv = tid >> 6;
        for (int i = tid; i < ECH; i += 256) {
            int e = base + i;
            if (e >= n) break;
            int d = __builtin_nontemporal_load(&dl[e]);
            int b = (g == 1) ? buckU(d) : buckA(d);
            atomicAdd(&hs4[wv][b], 1);
        }
        __syncthreads();
        int tot = hs4[0][tid] + hs4[1][tid] + hs4[2][tid] + hs4[3][tid];
        if (tot > 0) atomicAdd(&gcnt[g * 256 + tid], tot);
    } else if (bid < HB + PB_U) {
        // ---- user prologue: 8 rows, thread=(r, c), cols 4c..4c+3 ----
        int blk = bid - HB;
        int r = tid >> 5, c = tid & 31;
        int row = blk * 8 + r;
        xs[r][c] = user_x[(size_t)row * FU + c];  // F=32: one float/thread
        __syncthreads();
        int id = user_n_id[row];
        float4 e4 = *(const float4*)&user_emb[(size_t)id * H + 4 * c];
        float4 b4 = *(const float4*)&user_lin_b[4 * c];
        float4 acc = make_float4(e4.x + b4.x, e4.y + b4.y, e4.z + b4.z, e4.w + b4.w);
#pragma unroll
        for (int k = 0; k < FU; ++k) {
            float xk = xs[r][k];
            float4 w4 = *(const float4*)&user_lin_W[k * H + 4 * c];
            acc.x += xk * w4.x; acc.y += xk * w4.y;
            acc.z += xk * w4.z; acc.w += xk * w4.w;
        }
        uint2 pk;
        pk.x = (unsigned)f2bf(acc.x) | ((unsigned)f2bf(acc.y) << 16);
        pk.y = (unsigned)f2bf(acc.z) | ((unsigned)f2bf(acc.w) << 16);
        *(uint2*)&XBU[(size_t)row * H + 4 * c] = pk;
    } else if (bid < HB + PB_U + PB_A) {
        // ---- app prologue: 8 rows, F=64 ----
        int blk = bid - HB - PB_U;
        int r = tid >> 5, c = tid & 31;
        int row = blk * 8 + r;
        for (int i = tid; i < 8 * FA; i += 256)
            xs[i >> 6][i & 63] = app_x[(size_t)(blk * 8 + (i >> 6)) * FA + (i & 63)];
        __syncthreads();
        int id = app_n_id[row];
        float4 e4 = *(const float4*)&app_emb[(size_t)id * H + 4 * c];
        float4 b4 = *(const float4*)&app_lin_b[4 * c];
        float4 acc = make_float4(e4.x + b4.x, e4.y + b4.y, e4.z + b4.z, e4.w + b4.w);
#pragma unroll
        for (int k = 0; k < FA; ++k) {
            float xk = xs[r][k];
            float4 w4 = *(const float4*)&app_lin_W[k * H + 4 * c];
            acc.x += xk * w4.x; acc.y += xk * w4.y;
            acc.z += xk * w4.z; acc.w += xk * w4.w;
        }
        uint2 pk;
        pk.x = (unsigned)f2bf(acc.x) | ((unsigned)f2bf(acc.y) << 16);
        pk.y = (unsigned)f2bf(acc.z) | ((unsigned)f2bf(acc.w) << 16);
        *(uint2*)&XBA[(size_t)row * H + 4 * c] = pk;
    } else {
        // ---- weight pack: Bp fragment-ordered bf16, [Wmsg | Wself] 128x256 ----
        int idx = (bid - HB - PB_U - PB_A) * 256 + tid;  // 0 .. 131071
        int which = idx >> 15, li = idx & 32767;
        const float *Wm, *Ws;
        if (which == 0)      { Wm = Wm0; Ws = Ws0; }
        else if (which == 1) { Wm = Wm1; Ws = Ws1; }
        else if (which == 2) { Wm = Wm2; Ws = Ws2; }
        else                 { Wm = Wm3; Ws = Ws3; }
        int j = li & 7, l = (li >> 3) & 63, ks = (li >> 9) & 3, n = li >> 11;
        int ng = n * 16 + (l & 15);
        int kg = ks * 32 + (l >> 4) * 8 + j;
        float v = (n < 8) ? Wm[kg * H + ng] : Ws[kg * H + (ng - 128)];
        Bp[idx] = f2bf(v);
    }
}

// ---------------------------------------------------------------------------
// scan_coarse: 1 block; per graph: inclusive scan of 256 bucket counts ->
// cb (bucket row_ptr) and gcur (phaseA cursors = exclusive scan).
// ---------------------------------------------------------------------------
__global__ __launch_bounds__(256)
void scanc_kernel(const int* __restrict__ gcnt, int* __restrict__ cb,
                  int* __restrict__ gcur) {
    __shared__ int s[256];
    int t = threadIdx.x;
    for (int g = 0; g < 3; ++g) {
        int v = gcnt[g * 256 + t];
        s[t] = v;
        __syncthreads();
        for (int d = 1; d < 256; d <<= 1) {
            int a = (t >= d) ? s[t - d] : 0;
            __syncthreads();
            s[t] += a;
            __syncthreads();
        }
        cb[g * 257 + t + 1] = s[t];
        if (t == 0) cb[g * 257] = 0;
        gcur[g * 256 + t] = s[t] - v;
        __syncthreads();
    }
}

// ---------------------------------------------------------------------------
// phaseA: bin (payload,dst) pairs into exact bucket regions.
// ---------------------------------------------------------------------------
__global__ __launch_bounds__(256)
void phaseA_kernel(const int* __restrict__ s1, const int* __restrict__ d1,
                   const int* __restrict__ s2, const int* __restrict__ d2,
                   const int* __restrict__ d3, int* __restrict__ gcur,
                   int2* __restrict__ bp0, int2* __restrict__ bp1,
                   int2* __restrict__ bp2) {
    __shared__ int cnt[256], gb[256], cur[256];
    int bid = blockIdx.x, tid = threadIdx.x;
    int g, base, n;
    const int *dl, *sl;
    int2* bp;
    if (bid < BK_E)          { g = 0; base = bid * ECH;              dl = d1; sl = s1; n = NE;  bp = bp0; }
    else if (bid < 2 * BK_E) { g = 1; base = (bid - BK_E) * ECH;     dl = d2; sl = s2; n = NE;  bp = bp1; }
    else                     { g = 2; base = (bid - 2 * BK_E) * ECH; dl = d3; sl = nullptr; n = NEL; bp = bp2; }
    cnt[tid] = 0;
    cur[tid] = 0;
    __syncthreads();
    for (int i = tid; i < ECH; i += 256) {
        int e = base + i;
        if (e >= n) break;
        int d = __builtin_nontemporal_load(&dl[e]);
        int b = (g == 1) ? buckU(d) : buckA(d);
        atomicAdd(&cnt[b], 1);
    }
    __syncthreads();
    if (cnt[tid] > 0) gb[tid] = atomicAdd(&gcur[g * 256 + tid], cnt[tid]);
    __syncthreads();
    for (int i = tid; i < ECH; i += 256) {
        int e = base + i;
        if (e >= n) break;
        int d = __builtin_nontemporal_load(&dl[e]);
        int b = (g == 1) ? buckU(d) : buckA(d);
        int payload = (g == 2) ? e : __builtin_nontemporal_load(&sl[e]);
        int pos = gb[b] + atomicAdd(&cur[b], 1);
        bp[pos] = make_int2(payload, d);
    }
}

// ---------------------------------------------------------------------------
// phaseB: one block per (graph,bucket). Local per-dst hist + scan in LDS,
// write rp directly, scatter payloads into a contiguous ~16 KB region.
// ---------------------------------------------------------------------------
__global__ __launch_bounds__(256)
void phaseB_kernel(const int2* __restrict__ bp0, const int2* __restrict__ bp1,
                   const int2* __restrict__ bp2, const int* __restrict__ cb,
                   const int* __restrict__ el_src, int* __restrict__ eidx_ua,
                   int* __restrict__ eidx_au, int2* __restrict__ elp,
                   int* __restrict__ rp_a, int* __restrict__ rp_u,
                   int* __restrict__ rp_el) {
    __shared__ int cnt[400], rpl[400];
    int bid = blockIdx.x, tid = threadIdx.x;
    int g = bid >> 8, b = bid & 255;
    const int2* bp;
    int Nd;
    int* rp;
    if (g == 0)      { bp = bp0; Nd = NA; rp = rp_a;  }
    else if (g == 1) { bp = bp1; Nd = NU; rp = rp_u;  }
    else             { bp = bp2; Nd = NA; rp = rp_el; }
    int lo = (b * Nd + 255) >> 8, hi = ((b + 1) * Nd + 255) >> 8;
    int nd = hi - lo;
    int ebase = cb[g * 257 + b];
    int ecnt  = cb[g * 257 + b + 1] - ebase;
    for (int i = tid; i < nd; i += 256) cnt[i] = 0;
    __syncthreads();
    for (int i = tid; i < ecnt; i += 256) {
        long long v = __builtin_nontemporal_load((const long long*)&bp[ebase + i]);
        int d = (int)(v >> 32);
        atomicAdd(&cnt[d - lo], 1);
    }
    __syncthreads();
    if (tid == 0) {  // serial exclusive scan (nd <= 391)
        int run = 0;
        for (int i = 0; i < nd; ++i) { rpl[i] = run; run += cnt[i]; }
    }
    __syncthreads();
    for (int i = tid; i < nd; i += 256) {
        rp[lo + i] = ebase + rpl[i];
        cnt[i] = rpl[i];  // convert to cursor
    }
    if (b == 255 && tid == 0) rp[Nd] = ebase + ecnt;
    __syncthreads();
    for (int i = tid; i < ecnt; i += 256) {
        long long v = __builtin_nontemporal_load((const long long*)&bp[ebase + i]);
        int payload = (int)v, d = (int)(v >> 32);
        int pos = ebase + atomicAdd(&cnt[d - lo], 1);
        if (g == 0)      eidx_ua[pos] = payload;
        else if (g == 1) eidx_au[pos] = payload;
        else             elp[pos] = make_int2(el_src[payload], payload);
    }
}

// ---------------------------------------------------------------------------
// Merged dense GEMM (user + app halves): [Msg | Self] = A @ [Wmsg | Wself],
// M x 128 x 256, bf16 MFMA. Msg stored bf16, Self stored f32.
// ---------------------------------------------------------------------------
__global__ __launch_bounds__(256)
void gemm2_kernel(const unsigned short* __restrict__ Au,
                  const unsigned short* __restrict__ Aa,
                  const unsigned short* __restrict__ BpU,
                  const unsigned short* __restrict__ BpA,
                  unsigned short* __restrict__ MsgU, unsigned short* __restrict__ MsgA,
                  float* __restrict__ SelfU, float* __restrict__ SelfA) {
    __shared__ unsigned short Bs[32768];  // 64 KB packed weights
    int bid = blockIdx.x, tid = threadIdx.x;
    const unsigned short *A, *Bp;
    unsigned short* Msg;
    float* Self;
    int M, blk;
    if (bid < GG_U) { A = Au; Bp = BpU; Msg = MsgU; Self = SelfU; M = NU; blk = bid; }
    else            { A = Aa; Bp = BpA; Msg = MsgA; Self = SelfA; M = NA; blk = bid - GG_U; }
    {
        const int4* s = (const int4*)Bp;
        int4* d = (int4*)Bs;
#pragma unroll
        for (int i = 0; i < 16; ++i) d[tid + 256 * i] = s[tid + 256 * i];
    }
    __syncthreads();
    const int w = tid >> 6, l = tid & 63;
    const int l16 = l & 15, lg = l >> 4;
    const int r0 = blk * 128 + w * 32;
    const int ra0 = min(r0 + l16, M - 1);
    const int ra1 = min(r0 + 16 + l16, M - 1);
    f32x4 acc0[16], acc1[16];
#pragma unroll
    for (int n = 0; n < 16; ++n) {
        acc0[n] = f32x4{0.f, 0.f, 0.f, 0.f};
        acc1[n] = f32x4{0.f, 0.f, 0.f, 0.f};
    }
#pragma unroll
    for (int ks = 0; ks < 4; ++ks) {
        bf16x8 a0 = *(const bf16x8*)(A + (size_t)ra0 * H + ks * 32 + lg * 8);
        bf16x8 a1 = *(const bf16x8*)(A + (size_t)ra1 * H + ks * 32 + lg * 8);
#pragma unroll
        for (int n = 0; n < 16; ++n) {
            bf16x8 bf = *(const bf16x8*)&Bs[((n * 4 + ks) * 64 + l) * 8];
            acc0[n] = __builtin_amdgcn_mfma_f32_16x16x32_bf16(a0, bf, acc0[n], 0, 0, 0);
            acc1[n] = __builtin_amdgcn_mfma_f32_16x16x32_bf16(a1, bf, acc1[n], 0, 0, 0);
        }
    }
    // C/D layout (m89-verified): col = lane&15, row = (lane>>4)*4 + j
#pragma unroll
    for (int n = 0; n < 16; ++n) {
#pragma unroll
        for (int j = 0; j < 4; ++j) {
            int rr0 = r0 + lg * 4 + j;
            int rr1 = rr0 + 16;
            if (n < 8) {
                int c = n * 16 + l16;
                if (rr0 < M) Msg[(size_t)rr0 * H + c] = f2bf(acc0[n][j]);
                if (rr1 < M) Msg[(size_t)rr1 * H + c] = f2bf(acc1[n][j]);
            } else {
                int c = (n - 8) * 16 + l16;
                if (rr0 < M) Self[(size_t)rr0 * H + c] = acc0[n][j];
                if (rr1 < M) Self[(size_t)rr1 * H + c] = acc1[n][j];
            }
        }
    }
}

// ---------------------------------------------------------------------------
// Merged aggregate+finish: one wave per dst row; HALF-WAVE per edge, lane
// covers 4 cols (8 B bf16x4 loads). Cross-half combine via shfl_xor(32).
// 4 wave-iterations in flight = 8 edges, 32 B/lane outstanding.
// ---------------------------------------------------------------------------
template <bool RELU, bool OUTBF16>
__global__ __launch_bounds__(256)
void agg2_kernel(const unsigned short* __restrict__ MsgU,
                 const unsigned short* __restrict__ MsgA,
                 const int* __restrict__ rp_a, const int* __restrict__ rp_u,
                 const int* __restrict__ eidx_ua, const int* __restrict__ eidx_au,
                 const float* SelfA, const float* SelfU,
                 const float* __restrict__ bA, const float* __restrict__ bU,
                 void* outA, void* outU) {
    int bid = blockIdx.x;
    int w = threadIdx.x >> 6, l = threadIdx.x & 63;
    int half = l >> 5, c = l & 31;  // cols 4c..4c+3
    const unsigned short* Msg;
    const int *rp, *eidx;
    const float *Self, *bb_;
    void* outp;
    int row;
    if (bid < GA_A) { Msg = MsgU; rp = rp_a; eidx = eidx_ua; Self = SelfA; bb_ = bA; outp = outA; row = bid * 4 + w; }
    else            { Msg = MsgA; rp = rp_u; eidx = eidx_au; Self = SelfU; bb_ = bU; outp = outU; row = (bid - GA_A) * 4 + w; }
    int beg = rp[row], end = rp[row + 1];
    float s = 1.0f / fmaxf((float)(end - beg), 1.0f);
    float4 acc = make_float4(0.f, 0.f, 0.f, 0.f);
    int j = beg;
    for (; j + 7 < end; j += 8) {
        uint2 m0 = *(const uint2*)(Msg + (size_t)eidx[j     + half] * H + 4 * c);
        uint2 m1 = *(const uint2*)(Msg + (size_t)eidx[j + 2 + half] * H + 4 * c);
        uint2 m2 = *(const uint2*)(Msg + (size_t)eidx[j + 4 + half] * H + 4 * c);
        uint2 m3 = *(const uint2*)(Msg + (size_t)eidx[j + 6 + half] * H + 4 * c);
        acc.x += bf2f((unsigned short)(m0.x & 0xffff)) + bf2f((unsigned short)(m1.x & 0xffff)) +
                 bf2f((unsigned short)(m2.x & 0xffff)) + bf2f((unsigned short)(m3.x & 0xffff));
        acc.y += bf2f((unsigned short)(m0.x >> 16)) + bf2f((unsigned short)(m1.x >> 16)) +
                 bf2f((unsigned short)(m2.x >> 16)) + bf2f((unsigned short)(m3.x >> 16));
        acc.z += bf2f((unsigned short)(m0.y & 0xffff)) + bf2f((unsigned short)(m1.y & 0xffff)) +
                 bf2f((unsigned short)(m2.y & 0xffff)) + bf2f((unsigned short)(m3.y & 0xffff));
        acc.w += bf2f((unsigned short)(m0.y >> 16)) + bf2f((unsigned short)(m1.y >> 16)) +
                 bf2f((unsigned short)(m2.y >> 16)) + bf2f((unsigned short)(m3.y >> 16));
    }
    for (; j < end; j += 2) {
        int idx = j + half;
        if (idx < end) {
            uint2 m = *(const uint2*)(Msg + (size_t)eidx[idx] * H + 4 * c);
            acc.x += bf2f((unsigned short)(m.x & 0xffff));
            acc.y += bf2f((unsigned short)(m.x >> 16));
            acc.z += bf2f((unsigned short)(m.y & 0xffff));
            acc.w += bf2f((unsigned short)(m.y >> 16));
        }
    }
    // cross-half combine
    acc.x += __shfl_xor(acc.x, 32);
    acc.y += __shfl_xor(acc.y, 32);
    acc.z += __shfl_xor(acc.z, 32);
    acc.w += __shfl_xor(acc.w, 32);
    if (half == 0) {
        float4 sf = *(const float4*)(Self + (size_t)row * H + 4 * c);
        float4 bv = *(const float4*)(bb_ + 4 * c);
        float o0 = acc.x * s + sf.x + bv.x;
        float o1 = acc.y * s + sf.y + bv.y;
        float o2 = acc.z * s + sf.z + bv.z;
        float o3 = acc.w * s + sf.w + bv.w;
        if (RELU) {
            o0 = fmaxf(o0, 0.f); o1 = fmaxf(o1, 0.f);
            o2 = fmaxf(o2, 0.f); o3 = fmaxf(o3, 0.f);
        }
        if (OUTBF16) {
            uint2 pk;
            pk.x = (unsigned)f2bf(o0) | ((unsigned)f2bf(o1) << 16);
            pk.y = (unsigned)f2bf(o2) | ((unsigned)f2bf(o3) << 16);
            *(uint2*)((unsigned short*)outp + (size_t)row * H + 4 * c) = pk;
        } else {
            *(float4*)((float*)outp + (size_t)row * H + 4 * c) = make_float4(o0, o1, o2, o3);
        }
    }
}

// ---------------------------------------------------------------------------
// Head via el-CSR: one wave per app; HALF-WAVE per pair, lane covers 4 cols
// (16 B float4). xa row in registers; xor-reduce within half (width 32).
// ---------------------------------------------------------------------------
__global__ __launch_bounds__(256)
void pred_csr(const float* __restrict__ xu, const float* __restrict__ xa,
              const int* __restrict__ rp_el, const int2* __restrict__ elp,
              float* __restrict__ out) {
    int w = threadIdx.x >> 6, l = threadIdx.x & 63;
    int half = l >> 5, c = l & 31;
    int app = blockIdx.x * 4 + w;
    if (app >= NA) return;
    float4 a4 = *(const float4*)(xa + (size_t)app * H + 4 * c);
    int beg = rp_el[app], end = rp_el[app + 1];
    int j = beg;
    for (; j + 3 < end; j += 4) {
        int2 p0 = elp[j + half];
        int2 p1 = elp[j + 2 + half];
        float4 u0 = *(const float4*)(xu + (size_t)p0.x * H + 4 * c);
        float4 u1 = *(const float4*)(xu + (size_t)p1.x * H + 4 * c);
        float v0 = u0.x * a4.x + u0.y * a4.y + u0.z * a4.z + u0.w * a4.w;
        float v1 = u1.x * a4.x + u1.y * a4.y + u1.z * a4.z + u1.w * a4.w;
#pragma unroll
        for (int off = 16; off > 0; off >>= 1) {
            v0 += __shfl_xor(v0, off);
            v1 += __shfl_xor(v1, off);
        }
        if (c == 0) { out[p0.y] = v0; out[p1.y] = v1; }
    }
    for (; j < end; j += 2) {
        int idx = j + half;
        if (idx < end) {
            int2 p = elp[idx];
            float4 u = *(const float4*)(xu + (size_t)p.x * H + 4 * c);
            float v = u.x * a4.x + u.y * a4.y + u.z * a4.z + u.w * a4.w;
#pragma unroll
            for (int off = 16; off > 0; off >>= 1) v += __shfl_xor(v, off);
            if (c == 0) out[p.y] = v;
        }
    }
}

// ---------------------------------------------------------------------------
extern "C" void kernel_launch(void* const* d_in, const int* in_sizes, int n_in,
                              void* d_out, int out_size, void* d_ws, size_t ws_size,
                              hipStream_t stream) {
    const float* user_x     = (const float*)d_in[0];
    const float* app_x      = (const float*)d_in[1];
    const float* user_emb   = (const float*)d_in[2];
    const float* app_emb    = (const float*)d_in[3];
    const float* user_lin_W = (const float*)d_in[4];
    const float* user_lin_b = (const float*)d_in[5];
    const float* app_lin_W  = (const float*)d_in[6];
    const float* app_lin_b  = (const float*)d_in[7];
    const float* W_msg_ua1  = (const float*)d_in[8];
    const float* W_self_ua1 = (const float*)d_in[9];
    const float* b_ua1      = (const float*)d_in[10];
    const float* W_msg_au1  = (const float*)d_in[11];
    const float* W_self_au1 = (const float*)d_in[12];
    const float* b_au1      = (const float*)d_in[13];
    const float* W_msg_ua2  = (const float*)d_in[14];
    const float* W_self_ua2 = (const float*)d_in[15];
    const float* b_ua2      = (const float*)d_in[16];
    const float* W_msg_au2  = (const float*)d_in[17];
    const float* W_self_au2 = (const float*)d_in[18];
    const float* b_au2      = (const float*)d_in[19];
    const int*   user_n_id  = (const int*)d_in[20];
    const int*   app_n_id   = (const int*)d_in[21];
    const int*   e_src_u2a  = (const int*)d_in[22];
    const int*   e_dst_u2a  = (const int*)d_in[23];
    const int*   e_src_a2u  = (const int*)d_in[24];
    const int*   e_dst_a2u  = (const int*)d_in[25];
    const int*   el_src     = (const int*)d_in[26];
    const int*   el_dst     = (const int*)d_in[27];
    float* pred = (float*)d_out;
    (void)in_sizes; (void)n_in; (void)out_size; (void)ws_size;

    // ---- workspace layout (~156 MB; round-1 proved >=185 MB exists) ----
    char* p = (char*)d_ws;
    auto alloc = [&](size_t bytes) {
        char* r = p;
        p += (bytes + 255) & ~(size_t)255;
        return (void*)r;
    };
    float* SFU = (float*)alloc((size_t)NU * H * 4);   // Self_u -> xu2 in-place
    float* SFA = (float*)alloc((size_t)NA * H * 4);   // Self_a -> xa2 in-place
    unsigned short* XBU = (unsigned short*)alloc((size_t)NU * H * 2);  // x0_u then x1_u
    unsigned short* XBA = (unsigned short*)alloc((size_t)NA * H * 2);  // x0_a then x1_a
    unsigned short* MSGU = (unsigned short*)alloc((size_t)NU * H * 2);
    unsigned short* MSGA = (unsigned short*)alloc((size_t)NA * H * 2);
    int*  eidx_ua = (int*)alloc((size_t)NE * 4);
    int*  eidx_au = (int*)alloc((size_t)NE * 4);
    int2* elp     = (int2*)alloc((size_t)NEL * 8);    // (user, orig_e), app-sorted
    int2* bp0     = (int2*)alloc((size_t)NE * 8);     // phaseA bins (payload,dst)
    int2* bp1     = (int2*)alloc((size_t)NE * 8);
    int2* bp2     = (int2*)alloc((size_t)NEL * 8);
    int*  RP   = (int*)alloc((size_t)(NA + NU + NA + 3) * 4);  // [rp_a|rp_u|rp_el]
    int*  gcnt = (int*)alloc((size_t)768 * 4);
    int*  gcur = (int*)alloc((size_t)768 * 4);
    int*  cb   = (int*)alloc((size_t)(3 * 257) * 4);
    unsigned short* Bp = (unsigned short*)alloc((size_t)4 * 32768 * 2);

    int* rp_a  = RP;
    int* rp_u  = RP + NA + 1;
    int* rp_el = RP + NA + NU + 2;
    unsigned short* Bp_u1 = Bp;
    unsigned short* Bp_a1 = Bp + 32768;
    unsigned short* Bp_u2 = Bp + 2 * 32768;
    unsigned short* Bp_a2 = Bp + 3 * 32768;

    // ---- K1: hist_coarse + prologues + weight pack (independent, merged) ----
    hipMemsetAsync(gcnt, 0, 768 * 4, stream);
    k1_kernel<<<HB + PB_U + PB_A + PACKB, 256, 0, stream>>>(
        e_dst_u2a, e_dst_a2u, el_dst, gcnt,
        user_x, user_emb, user_lin_W, user_lin_b, user_n_id, XBU,
        app_x, app_emb, app_lin_W, app_lin_b, app_n_id, XBA,
        W_msg_ua1, W_self_au1, W_msg_au1, W_self_ua1,
        W_msg_ua2, W_self_au2, W_msg_au2, W_self_ua2, Bp);

    // ---- bucket-sort CSR build ----
    scanc_kernel<<<1, 256, 0, stream>>>(gcnt, cb, gcur);
    phaseA_kernel<<<HB, 256, 0, stream>>>(e_src_u2a, e_dst_u2a, e_src_a2u,
                                          e_dst_a2u, el_dst, gcur, bp0, bp1, bp2);
    phaseB_kernel<<<768, 256, 0, stream>>>(bp0, bp1, bp2, cb, el_src,
                                           eidx_ua, eidx_au, elp,
                                           rp_a, rp_u, rp_el);

    // ---- layer 1: GEMMs then aggregate+finish -> bf16 x1 ----
    gemm2_kernel<<<GG_U + GG_A, 256, 0, stream>>>(XBU, XBA, Bp_u1, Bp_a1,
                                                  MSGU, MSGA, SFU, SFA);
    agg2_kernel<true, true><<<GA_A + GA_U, 256, 0, stream>>>(
        MSGU, MSGA, rp_a, rp_u, eidx_ua, eidx_au, SFA, SFU, b_ua1, b_au1,
        XBA, XBU);

    // ---- layer 2: GEMMs then aggregate+finish -> f32 x2 in-place over Self ----
    gemm2_kernel<<<GG_U + GG_A, 256, 0, stream>>>(XBU, XBA, Bp_u2, Bp_a2,
                                                  MSGU, MSGA, SFU, SFA);
    agg2_kernel<false, false><<<GA_A + GA_U, 256, 0, stream>>>(
        MSGU, MSGA, rp_a, rp_u, eidx_ua, eidx_au, SFA, SFU, b_ua2, b_au2,
        SFA, SFU);

    // ---- head ----
    pred_csr<<<NA / 4, 256, 0, stream>>>(SFU, SFA, rp_el, elp, pred);
}

// Round 8
// 386.737 us; speedup vs baseline: 19.5463x; 1.1379x over previous
//
#include <hip/hip_runtime.h>

// Problem constants (match reference setup_inputs)
constexpr int NU  = 100000;   // users
constexpr int NA  = 20000;    // apps
constexpr int FU  = 32;
constexpr int FA  = 64;
constexpr int H   = 128;
constexpr int NE  = 1000000;  // edges per direction
constexpr int NEL = 500000;   // labeled pairs

// bucket-sort geometry
constexpr int ECH  = 8192;                // edges per hist/phaseA block
constexpr int BK_E = (NE + ECH - 1) / ECH;   // 123
constexpr int BK_L = (NEL + ECH - 1) / ECH;  // 62
constexpr int HB   = 2 * BK_E + BK_L;        // 308 hist blocks
constexpr int PB_U = NU / 32;             // 3125 prologue blocks (32 rows each)
constexpr int PB_A = NA / 32;             // 625
constexpr int PACKB = 512;                // 4*32768 / 256
constexpr int GG_U = (NU + 127) / 128;    // 782
constexpr int GG_A = (NA + 127) / 128;    // 157
constexpr int GA_A = NA / 4;              // 5000
constexpr int GA_U = NU / 4;              // 25000

using bf16x8 = __attribute__((ext_vector_type(8))) short;
using f32x4  = __attribute__((ext_vector_type(4))) float;

__device__ inline unsigned short f2bf(float f) {
    union { float f; unsigned u; } x; x.f = f;
    unsigned u = x.u;
    return (unsigned short)((u + 0x7fffu + ((u >> 16) & 1u)) >> 16);  // RNE
}
__device__ inline float bf2f(unsigned short s) {
    union { unsigned u; float f; } x; x.u = ((unsigned)s) << 16;
    return x.f;
}
__device__ inline int buckA(int d) { return (int)(((unsigned)d * 256u) / 20000u); }
__device__ inline int buckU(int d) { return (int)(((unsigned)d * 256u) / 100000u); }

// ---------------------------------------------------------------------------
// K1 mega-kernel: [hist_coarse | prologue_user | prologue_app | pack]
// Prologue: 32 rows/block, thread=(row-slot, 4-col group) owning 4 rows —
// each W float4 load feeds 16 FMAs (4 rows x 4 cols), 4 independent chains.
// ---------------------------------------------------------------------------
__global__ __launch_bounds__(256)
void k1_kernel(const int* __restrict__ d1, const int* __restrict__ d2,
               const int* __restrict__ d3, int* __restrict__ gcnt,
               const float* __restrict__ user_x, const float* __restrict__ user_emb,
               const float* __restrict__ user_lin_W, const float* __restrict__ user_lin_b,
               const int* __restrict__ user_n_id, unsigned short* __restrict__ XBU,
               const float* __restrict__ app_x, const float* __restrict__ app_emb,
               const float* __restrict__ app_lin_W, const float* __restrict__ app_lin_b,
               const int* __restrict__ app_n_id, unsigned short* __restrict__ XBA,
               const float* __restrict__ Wm0, const float* __restrict__ Ws0,
               const float* __restrict__ Wm1, const float* __restrict__ Ws1,
               const float* __restrict__ Wm2, const float* __restrict__ Ws2,
               const float* __restrict__ Wm3, const float* __restrict__ Ws3,
               unsigned short* __restrict__ Bp) {
    __shared__ float xs[32][64];   // 8 KB (also used as 4x256 int hist)
    int bid = blockIdx.x, tid = threadIdx.x;
    if (bid < HB) {
        // ---- coarse 256-bucket histogram over the 3 dst lists ----
        int* hs4 = (int*)xs;  // [4][256]
        int g, base, n;
        const int* dl;
        if (bid < BK_E)          { g = 0; base = bid * ECH;              dl = d1; n = NE;  }
        else if (bid < 2 * BK_E) { g = 1; base = (bid - BK_E) * ECH;     dl = d2; n = NE;  }
        else                     { g = 2; base = (bid - 2 * BK_E) * ECH; dl = d3; n = NEL; }
        for (int i = tid; i < 1024; i += 256) hs4[i] = 0;
        __syncthreads();
        int wv = tid >> 6;
        for (int i = tid; i < ECH; i += 256) {
            int e = base + i;
            if (e >= n) break;
            int d = __builtin_nontemporal_load(&dl[e]);
            int b = (g == 1) ? buckU(d) : buckA(d);
            atomicAdd(&hs4[wv * 256 + b], 1);
        }
        __syncthreads();
        int tot = hs4[tid] + hs4[256 + tid] + hs4[512 + tid] + hs4[768 + tid];
        if (tot > 0) atomicAdd(&gcnt[g * 256 + tid], tot);
    } else if (bid < HB + PB_U) {
        // ---- user prologue: 32 rows/block, thread owns rows r,r+8,r+16,r+24 ----
        int blk = bid - HB;
        int r = tid >> 5, c = tid & 31;
        int row0 = blk * 32;
        for (int i = tid; i < 32 * FU; i += 256)
            xs[i >> 5][i & 31] = user_x[(size_t)row0 * FU + i];
        __syncthreads();
        float4 acc[4];
#pragma unroll
        for (int q = 0; q < 4; ++q) {
            int row = row0 + r + 8 * q;
            int id = user_n_id[row];
            float4 e4 = *(const float4*)&user_emb[(size_t)id * H + 4 * c];
            float4 b4 = *(const float4*)&user_lin_b[4 * c];
            acc[q] = make_float4(e4.x + b4.x, e4.y + b4.y, e4.z + b4.z, e4.w + b4.w);
        }
#pragma unroll 8
        for (int k = 0; k < FU; ++k) {
            float4 w4 = *(const float4*)&user_lin_W[k * H + 4 * c];
#pragma unroll
            for (int q = 0; q < 4; ++q) {
                float xk = xs[r + 8 * q][k];
                acc[q].x += xk * w4.x; acc[q].y += xk * w4.y;
                acc[q].z += xk * w4.z; acc[q].w += xk * w4.w;
            }
        }
#pragma unroll
        for (int q = 0; q < 4; ++q) {
            int row = row0 + r + 8 * q;
            uint2 pk;
            pk.x = (unsigned)f2bf(acc[q].x) | ((unsigned)f2bf(acc[q].y) << 16);
            pk.y = (unsigned)f2bf(acc[q].z) | ((unsigned)f2bf(acc[q].w) << 16);
            *(uint2*)&XBU[(size_t)row * H + 4 * c] = pk;
        }
    } else if (bid < HB + PB_U + PB_A) {
        // ---- app prologue: 32 rows/block, F=64 ----
        int blk = bid - HB - PB_U;
        int r = tid >> 5, c = tid & 31;
        int row0 = blk * 32;
        for (int i = tid; i < 32 * FA; i += 256)
            xs[i >> 6][i & 63] = app_x[(size_t)row0 * FA + i];
        __syncthreads();
        float4 acc[4];
#pragma unroll
        for (int q = 0; q < 4; ++q) {
            int row = row0 + r + 8 * q;
            int id = app_n_id[row];
            float4 e4 = *(const float4*)&app_emb[(size_t)id * H + 4 * c];
            float4 b4 = *(const float4*)&app_lin_b[4 * c];
            acc[q] = make_float4(e4.x + b4.x, e4.y + b4.y, e4.z + b4.z, e4.w + b4.w);
        }
#pragma unroll 8
        for (int k = 0; k < FA; ++k) {
            float4 w4 = *(const float4*)&app_lin_W[k * H + 4 * c];
#pragma unroll
            for (int q = 0; q < 4; ++q) {
                float xk = xs[r + 8 * q][k];
                acc[q].x += xk * w4.x; acc[q].y += xk * w4.y;
                acc[q].z += xk * w4.z; acc[q].w += xk * w4.w;
            }
        }
#pragma unroll
        for (int q = 0; q < 4; ++q) {
            int row = row0 + r + 8 * q;
            uint2 pk;
            pk.x = (unsigned)f2bf(acc[q].x) | ((unsigned)f2bf(acc[q].y) << 16);
            pk.y = (unsigned)f2bf(acc[q].z) | ((unsigned)f2bf(acc[q].w) << 16);
            *(uint2*)&XBA[(size_t)row * H + 4 * c] = pk;
        }
    } else {
        // ---- weight pack: Bp fragment-ordered bf16, [Wmsg | Wself] 128x256 ----
        int idx = (bid - HB - PB_U - PB_A) * 256 + tid;  // 0 .. 131071
        int which = idx >> 15, li = idx & 32767;
        const float *Wm, *Ws;
        if (which == 0)      { Wm = Wm0; Ws = Ws0; }
        else if (which == 1) { Wm = Wm1; Ws = Ws1; }
        else if (which == 2) { Wm = Wm2; Ws = Ws2; }
        else                 { Wm = Wm3; Ws = Ws3; }
        int j = li & 7, l = (li >> 3) & 63, ks = (li >> 9) & 3, n = li >> 11;
        int ng = n * 16 + (l & 15);
        int kg = ks * 32 + (l >> 4) * 8 + j;
        float v = (n < 8) ? Wm[kg * H + ng] : Ws[kg * H + (ng - 128)];
        Bp[idx] = f2bf(v);
    }
}

// ---------------------------------------------------------------------------
// scan_coarse: 1 block; per graph: inclusive scan of 256 bucket counts ->
// cb (bucket row_ptr) and gcur (phaseA cursors = exclusive scan).
// ---------------------------------------------------------------------------
__global__ __launch_bounds__(256)
void scanc_kernel(const int* __restrict__ gcnt, int* __restrict__ cb,
                  int* __restrict__ gcur) {
    __shared__ int s[256];
    int t = threadIdx.x;
    for (int g = 0; g < 3; ++g) {
        int v = gcnt[g * 256 + t];
        s[t] = v;
        __syncthreads();
        for (int d = 1; d < 256; d <<= 1) {
            int a = (t >= d) ? s[t - d] : 0;
            __syncthreads();
            s[t] += a;
            __syncthreads();
        }
        cb[g * 257 + t + 1] = s[t];
        if (t == 0) cb[g * 257] = 0;
        gcur[g * 256 + t] = s[t] - v;
        __syncthreads();
    }
}

// ---------------------------------------------------------------------------
// phaseA: bin (payload,dst) pairs into exact bucket regions.
// ---------------------------------------------------------------------------
__global__ __launch_bounds__(256)
void phaseA_kernel(const int* __restrict__ s1, const int* __restrict__ d1,
                   const int* __restrict__ s2, const int* __restrict__ d2,
                   const int* __restrict__ d3, int* __restrict__ gcur,
                   int2* __restrict__ bp0, int2* __restrict__ bp1,
                   int2* __restrict__ bp2) {
    __shared__ int cnt[256], gb[256], cur[256];
    int bid = blockIdx.x, tid = threadIdx.x;
    int g, base, n;
    const int *dl, *sl;
    int2* bp;
    if (bid < BK_E)          { g = 0; base = bid * ECH;              dl = d1; sl = s1; n = NE;  bp = bp0; }
    else if (bid < 2 * BK_E) { g = 1; base = (bid - BK_E) * ECH;     dl = d2; sl = s2; n = NE;  bp = bp1; }
    else                     { g = 2; base = (bid - 2 * BK_E) * ECH; dl = d3; sl = nullptr; n = NEL; bp = bp2; }
    cnt[tid] = 0;
    cur[tid] = 0;
    __syncthreads();
    for (int i = tid; i < ECH; i += 256) {
        int e = base + i;
        if (e >= n) break;
        int d = __builtin_nontemporal_load(&dl[e]);
        int b = (g == 1) ? buckU(d) : buckA(d);
        atomicAdd(&cnt[b], 1);
    }
    __syncthreads();
    if (cnt[tid] > 0) gb[tid] = atomicAdd(&gcur[g * 256 + tid], cnt[tid]);
    __syncthreads();
    for (int i = tid; i < ECH; i += 256) {
        int e = base + i;
        if (e >= n) break;
        int d = __builtin_nontemporal_load(&dl[e]);
        int b = (g == 1) ? buckU(d) : buckA(d);
        int payload = (g == 2) ? e : __builtin_nontemporal_load(&sl[e]);
        int pos = gb[b] + atomicAdd(&cur[b], 1);
        bp[pos] = make_int2(payload, d);
    }
}

// ---------------------------------------------------------------------------
// phaseB: one block per (graph,bucket). Local per-dst hist + scan in LDS,
// write rp directly, scatter payloads into a contiguous ~16 KB region.
// ---------------------------------------------------------------------------
__global__ __launch_bounds__(256)
void phaseB_kernel(const int2* __restrict__ bp0, const int2* __restrict__ bp1,
                   const int2* __restrict__ bp2, const int* __restrict__ cb,
                   const int* __restrict__ el_src, int* __restrict__ eidx_ua,
                   int* __restrict__ eidx_au, int2* __restrict__ elp,
                   int* __restrict__ rp_a, int* __restrict__ rp_u,
                   int* __restrict__ rp_el) {
    __shared__ int cnt[400], rpl[400];
    int bid = blockIdx.x, tid = threadIdx.x;
    int g = bid >> 8, b = bid & 255;
    const int2* bp;
    int Nd;
    int* rp;
    if (g == 0)      { bp = bp0; Nd = NA; rp = rp_a;  }
    else if (g == 1) { bp = bp1; Nd = NU; rp = rp_u;  }
    else             { bp = bp2; Nd = NA; rp = rp_el; }
    int lo = (b * Nd + 255) >> 8, hi = ((b + 1) * Nd + 255) >> 8;
    int nd = hi - lo;
    int ebase = cb[g * 257 + b];
    int ecnt  = cb[g * 257 + b + 1] - ebase;
    for (int i = tid; i < nd; i += 256) cnt[i] = 0;
    __syncthreads();
    for (int i = tid; i < ecnt; i += 256) {
        long long v = __builtin_nontemporal_load((const long long*)&bp[ebase + i]);
        int d = (int)(v >> 32);
        atomicAdd(&cnt[d - lo], 1);
    }
    __syncthreads();
    if (tid == 0) {  // serial exclusive scan (nd <= 391)
        int run = 0;
        for (int i = 0; i < nd; ++i) { rpl[i] = run; run += cnt[i]; }
    }
    __syncthreads();
    for (int i = tid; i < nd; i += 256) {
        rp[lo + i] = ebase + rpl[i];
        cnt[i] = rpl[i];  // convert to cursor
    }
    if (b == 255 && tid == 0) rp[Nd] = ebase + ecnt;
    __syncthreads();
    for (int i = tid; i < ecnt; i += 256) {
        long long v = __builtin_nontemporal_load((const long long*)&bp[ebase + i]);
        int payload = (int)v, d = (int)(v >> 32);
        int pos = ebase + atomicAdd(&cnt[d - lo], 1);
        if (g == 0)      eidx_ua[pos] = payload;
        else if (g == 1) eidx_au[pos] = payload;
        else             elp[pos] = make_int2(el_src[payload], payload);
    }
}

// ---------------------------------------------------------------------------
// Merged dense GEMM (user + app halves): [Msg | Self] = A @ [Wmsg | Wself],
// M x 128 x 256, bf16 MFMA. Msg stored bf16, Self stored f32.
// ---------------------------------------------------------------------------
__global__ __launch_bounds__(256)
void gemm2_kernel(const unsigned short* __restrict__ Au,
                  const unsigned short* __restrict__ Aa,
                  const unsigned short* __restrict__ BpU,
                  const unsigned short* __restrict__ BpA,
                  unsigned short* __restrict__ MsgU, unsigned short* __restrict__ MsgA,
                  float* __restrict__ SelfU, float* __restrict__ SelfA) {
    __shared__ unsigned short Bs[32768];  // 64 KB packed weights
    int bid = blockIdx.x, tid = threadIdx.x;
    const unsigned short *A, *Bp;
    unsigned short* Msg;
    float* Self;
    int M, blk;
    if (bid < GG_U) { A = Au; Bp = BpU; Msg = MsgU; Self = SelfU; M = NU; blk = bid; }
    else            { A = Aa; Bp = BpA; Msg = MsgA; Self = SelfA; M = NA; blk = bid - GG_U; }
    {
        const int4* s = (const int4*)Bp;
        int4* d = (int4*)Bs;
#pragma unroll
        for (int i = 0; i < 16; ++i) d[tid + 256 * i] = s[tid + 256 * i];
    }
    __syncthreads();
    const int w = tid >> 6, l = tid & 63;
    const int l16 = l & 15, lg = l >> 4;
    const int r0 = blk * 128 + w * 32;
    const int ra0 = min(r0 + l16, M - 1);
    const int ra1 = min(r0 + 16 + l16, M - 1);
    f32x4 acc0[16], acc1[16];
#pragma unroll
    for (int n = 0; n < 16; ++n) {
        acc0[n] = f32x4{0.f, 0.f, 0.f, 0.f};
        acc1[n] = f32x4{0.f, 0.f, 0.f, 0.f};
    }
#pragma unroll
    for (int ks = 0; ks < 4; ++ks) {
        bf16x8 a0 = *(const bf16x8*)(A + (size_t)ra0 * H + ks * 32 + lg * 8);
        bf16x8 a1 = *(const bf16x8*)(A + (size_t)ra1 * H + ks * 32 + lg * 8);
#pragma unroll
        for (int n = 0; n < 16; ++n) {
            bf16x8 bf = *(const bf16x8*)&Bs[((n * 4 + ks) * 64 + l) * 8];
            acc0[n] = __builtin_amdgcn_mfma_f32_16x16x32_bf16(a0, bf, acc0[n], 0, 0, 0);
            acc1[n] = __builtin_amdgcn_mfma_f32_16x16x32_bf16(a1, bf, acc1[n], 0, 0, 0);
        }
    }
    // C/D layout (m89-verified): col = lane&15, row = (lane>>4)*4 + j
#pragma unroll
    for (int n = 0; n < 16; ++n) {
#pragma unroll
        for (int j = 0; j < 4; ++j) {
            int rr0 = r0 + lg * 4 + j;
            int rr1 = rr0 + 16;
            if (n < 8) {
                int c = n * 16 + l16;
                if (rr0 < M) Msg[(size_t)rr0 * H + c] = f2bf(acc0[n][j]);
                if (rr1 < M) Msg[(size_t)rr1 * H + c] = f2bf(acc1[n][j]);
            } else {
                int c = (n - 8) * 16 + l16;
                if (rr0 < M) Self[(size_t)rr0 * H + c] = acc0[n][j];
                if (rr1 < M) Self[(size_t)rr1 * H + c] = acc1[n][j];
            }
        }
    }
}

// ---------------------------------------------------------------------------
// Merged aggregate+finish: one wave per dst row; HALF-WAVE per edge, lane
// covers 4 cols (8 B bf16x4 loads). Cross-half combine via shfl_xor(32).
// PREDICATED main loop (clamped index + mask-FMA): all 4 loads issue even on
// short rows (avg user degree = 10) -> full memory-level parallelism.
// ---------------------------------------------------------------------------
template <bool RELU, bool OUTBF16>
__global__ __launch_bounds__(256)
void agg2_kernel(const unsigned short* __restrict__ MsgU,
                 const unsigned short* __restrict__ MsgA,
                 const int* __restrict__ rp_a, const int* __restrict__ rp_u,
                 const int* __restrict__ eidx_ua, const int* __restrict__ eidx_au,
                 const float* SelfA, const float* SelfU,
                 const float* __restrict__ bA, const float* __restrict__ bU,
                 void* outA, void* outU) {
    int bid = blockIdx.x;
    int w = threadIdx.x >> 6, l = threadIdx.x & 63;
    int half = l >> 5, c = l & 31;  // cols 4c..4c+3
    const unsigned short* Msg;
    const int *rp, *eidx;
    const float *Self, *bb_;
    void* outp;
    int row;
    if (bid < GA_A) { Msg = MsgU; rp = rp_a; eidx = eidx_ua; Self = SelfA; bb_ = bA; outp = outA; row = bid * 4 + w; }
    else            { Msg = MsgA; rp = rp_u; eidx = eidx_au; Self = SelfU; bb_ = bU; outp = outU; row = (bid - GA_A) * 4 + w; }
    int beg = rp[row], end = rp[row + 1];
    float s = 1.0f / fmaxf((float)(end - beg), 1.0f);
    float4 acc = make_float4(0.f, 0.f, 0.f, 0.f);
    for (int j = beg; j < end; j += 8) {
#pragma unroll
        for (int k = 0; k < 4; ++k) {
            int idx = j + 2 * k + half;
            int src = eidx[min(idx, end - 1)];
            uint2 m = *(const uint2*)(Msg + (size_t)src * H + 4 * c);
            float mask = (idx < end) ? 1.f : 0.f;
            acc.x += mask * bf2f((unsigned short)(m.x & 0xffff));
            acc.y += mask * bf2f((unsigned short)(m.x >> 16));
            acc.z += mask * bf2f((unsigned short)(m.y & 0xffff));
            acc.w += mask * bf2f((unsigned short)(m.y >> 16));
        }
    }
    // cross-half combine
    acc.x += __shfl_xor(acc.x, 32);
    acc.y += __shfl_xor(acc.y, 32);
    acc.z += __shfl_xor(acc.z, 32);
    acc.w += __shfl_xor(acc.w, 32);
    if (half == 0) {
        float4 sf = *(const float4*)(Self + (size_t)row * H + 4 * c);
        float4 bv = *(const float4*)(bb_ + 4 * c);
        float o0 = acc.x * s + sf.x + bv.x;
        float o1 = acc.y * s + sf.y + bv.y;
        float o2 = acc.z * s + sf.z + bv.z;
        float o3 = acc.w * s + sf.w + bv.w;
        if (RELU) {
            o0 = fmaxf(o0, 0.f); o1 = fmaxf(o1, 0.f);
            o2 = fmaxf(o2, 0.f); o3 = fmaxf(o3, 0.f);
        }
        if (OUTBF16) {
            uint2 pk;
            pk.x = (unsigned)f2bf(o0) | ((unsigned)f2bf(o1) << 16);
            pk.y = (unsigned)f2bf(o2) | ((unsigned)f2bf(o3) << 16);
            *(uint2*)((unsigned short*)outp + (size_t)row * H + 4 * c) = pk;
        } else {
            *(float4*)((float*)outp + (size_t)row * H + 4 * c) = make_float4(o0, o1, o2, o3);
        }
    }
}

// ---------------------------------------------------------------------------
// Head via el-CSR: one wave per app; HALF-WAVE per pair, lane covers 4 cols
// (16 B float4). xa row in registers; xor-reduce within half (width 32).
// ---------------------------------------------------------------------------
__global__ __launch_bounds__(256)
void pred_csr(const float* __restrict__ xu, const float* __restrict__ xa,
              const int* __restrict__ rp_el, const int2* __restrict__ elp,
              float* __restrict__ out) {
    int w = threadIdx.x >> 6, l = threadIdx.x & 63;
    int half = l >> 5, c = l & 31;
    int app = blockIdx.x * 4 + w;
    if (app >= NA) return;
    float4 a4 = *(const float4*)(xa + (size_t)app * H + 4 * c);
    int beg = rp_el[app], end = rp_el[app + 1];
    int j = beg;
    for (; j + 3 < end; j += 4) {
        int2 p0 = elp[j + half];
        int2 p1 = elp[j + 2 + half];
        float4 u0 = *(const float4*)(xu + (size_t)p0.x * H + 4 * c);
        float4 u1 = *(const float4*)(xu + (size_t)p1.x * H + 4 * c);
        float v0 = u0.x * a4.x + u0.y * a4.y + u0.z * a4.z + u0.w * a4.w;
        float v1 = u1.x * a4.x + u1.y * a4.y + u1.z * a4.z + u1.w * a4.w;
#pragma unroll
        for (int off = 16; off > 0; off >>= 1) {
            v0 += __shfl_xor(v0, off);
            v1 += __shfl_xor(v1, off);
        }
        if (c == 0) { out[p0.y] = v0; out[p1.y] = v1; }
    }
    for (; j < end; j += 2) {
        int idx = j + half;
        if (idx < end) {
            int2 p = elp[idx];
            float4 u = *(const float4*)(xu + (size_t)p.x * H + 4 * c);
            float v = u.x * a4.x + u.y * a4.y + u.z * a4.z + u.w * a4.w;
#pragma unroll
            for (int off = 16; off > 0; off >>= 1) v += __shfl_xor(v, off);
            if (c == 0) out[p.y] = v;
        }
    }
}

// ---------------------------------------------------------------------------
extern "C" void kernel_launch(void* const* d_in, const int* in_sizes, int n_in,
                              void* d_out, int out_size, void* d_ws, size_t ws_size,
                              hipStream_t stream) {
    const float* user_x     = (const float*)d_in[0];
    const float* app_x      = (const float*)d_in[1];
    const float* user_emb   = (const float*)d_in[2];
    const float* app_emb    = (const float*)d_in[3];
    const float* user_lin_W = (const float*)d_in[4];
    const float* user_lin_b = (const float*)d_in[5];
    const float* app_lin_W  = (const float*)d_in[6];
    const float* app_lin_b  = (const float*)d_in[7];
    const float* W_msg_ua1  = (const float*)d_in[8];
    const float* W_self_ua1 = (const float*)d_in[9];
    const float* b_ua1      = (const float*)d_in[10];
    const float* W_msg_au1  = (const float*)d_in[11];
    const float* W_self_au1 = (const float*)d_in[12];
    const float* b_au1      = (const float*)d_in[13];
    const float* W_msg_ua2  = (const float*)d_in[14];
    const float* W_self_ua2 = (const float*)d_in[15];
    const float* b_ua2      = (const float*)d_in[16];
    const float* W_msg_au2  = (const float*)d_in[17];
    const float* W_self_au2 = (const float*)d_in[18];
    const float* b_au2      = (const float*)d_in[19];
    const int*   user_n_id  = (const int*)d_in[20];
    const int*   app_n_id   = (const int*)d_in[21];
    const int*   e_src_u2a  = (const int*)d_in[22];
    const int*   e_dst_u2a  = (const int*)d_in[23];
    const int*   e_src_a2u  = (const int*)d_in[24];
    const int*   e_dst_a2u  = (const int*)d_in[25];
    const int*   el_src     = (const int*)d_in[26];
    const int*   el_dst     = (const int*)d_in[27];
    float* pred = (float*)d_out;
    (void)in_sizes; (void)n_in; (void)out_size; (void)ws_size;

    // ---- workspace layout (~156 MB; round-1 proved >=185 MB exists) ----
    char* p = (char*)d_ws;
    auto alloc = [&](size_t bytes) {
        char* r = p;
        p += (bytes + 255) & ~(size_t)255;
        return (void*)r;
    };
    float* SFU = (float*)alloc((size_t)NU * H * 4);   // Self_u -> xu2 in-place
    float* SFA = (float*)alloc((size_t)NA * H * 4);   // Self_a -> xa2 in-place
    unsigned short* XBU = (unsigned short*)alloc((size_t)NU * H * 2);  // x0_u then x1_u
    unsigned short* XBA = (unsigned short*)alloc((size_t)NA * H * 2);  // x0_a then x1_a
    unsigned short* MSGU = (unsigned short*)alloc((size_t)NU * H * 2);
    unsigned short* MSGA = (unsigned short*)alloc((size_t)NA * H * 2);
    int*  eidx_ua = (int*)alloc((size_t)NE * 4);
    int*  eidx_au = (int*)alloc((size_t)NE * 4);
    int2* elp     = (int2*)alloc((size_t)NEL * 8);    // (user, orig_e), app-sorted
    int2* bp0     = (int2*)alloc((size_t)NE * 8);     // phaseA bins (payload,dst)
    int2* bp1     = (int2*)alloc((size_t)NE * 8);
    int2* bp2     = (int2*)alloc((size_t)NEL * 8);
    int*  RP   = (int*)alloc((size_t)(NA + NU + NA + 3) * 4);  // [rp_a|rp_u|rp_el]
    int*  gcnt = (int*)alloc((size_t)768 * 4);
    int*  gcur = (int*)alloc((size_t)768 * 4);
    int*  cb   = (int*)alloc((size_t)(3 * 257) * 4);
    unsigned short* Bp = (unsigned short*)alloc((size_t)4 * 32768 * 2);

    int* rp_a  = RP;
    int* rp_u  = RP + NA + 1;
    int* rp_el = RP + NA + NU + 2;
    unsigned short* Bp_u1 = Bp;
    unsigned short* Bp_a1 = Bp + 32768;
    unsigned short* Bp_u2 = Bp + 2 * 32768;
    unsigned short* Bp_a2 = Bp + 3 * 32768;

    // ---- K1: hist_coarse + prologues + weight pack (independent, merged) ----
    hipMemsetAsync(gcnt, 0, 768 * 4, stream);
    k1_kernel<<<HB + PB_U + PB_A + PACKB, 256, 0, stream>>>(
        e_dst_u2a, e_dst_a2u, el_dst, gcnt,
        user_x, user_emb, user_lin_W, user_lin_b, user_n_id, XBU,
        app_x, app_emb, app_lin_W, app_lin_b, app_n_id, XBA,
        W_msg_ua1, W_self_au1, W_msg_au1, W_self_ua1,
        W_msg_ua2, W_self_au2, W_msg_au2, W_self_ua2, Bp);

    // ---- bucket-sort CSR build ----
    scanc_kernel<<<1, 256, 0, stream>>>(gcnt, cb, gcur);
    phaseA_kernel<<<HB, 256, 0, stream>>>(e_src_u2a, e_dst_u2a, e_src_a2u,
                                          e_dst_a2u, el_dst, gcur, bp0, bp1, bp2);
    phaseB_kernel<<<768, 256, 0, stream>>>(bp0, bp1, bp2, cb, el_src,
                                           eidx_ua, eidx_au, elp,
                                           rp_a, rp_u, rp_el);

    // ---- layer 1: GEMMs then aggregate+finish -> bf16 x1 ----
    gemm2_kernel<<<GG_U + GG_A, 256, 0, stream>>>(XBU, XBA, Bp_u1, Bp_a1,
                                                  MSGU, MSGA, SFU, SFA);
    agg2_kernel<true, true><<<GA_A + GA_U, 256, 0, stream>>>(
        MSGU, MSGA, rp_a, rp_u, eidx_ua, eidx_au, SFA, SFU, b_ua1, b_au1,
        XBA, XBU);

    // ---- layer 2: GEMMs then aggregate+finish -> f32 x2 in-place over Self ----
    gemm2_kernel<<<GG_U + GG_A, 256, 0, stream>>>(XBU, XBA, Bp_u2, Bp_a2,
                                                  MSGU, MSGA, SFU, SFA);
    agg2_kernel<false, false><<<GA_A + GA_U, 256, 0, stream>>>(
        MSGU, MSGA, rp_a, rp_u, eidx_ua, eidx_au, SFA, SFU, b_ua2, b_au2,
        SFA, SFU);

    // ---- head ----
    pred_csr<<<NA / 4, 256, 0, stream>>>(SFU, SFA, rp_el, elp, pred);
}